// Round 2
// baseline (4041.205 us; speedup 1.0000x reference)
//
#include <hip/hip_runtime.h>
#include <math.h>

// ---------------------------------------------------------------------------
// MACE layer, f32 reference-faithful implementation (round 2: fix k_transpose
// grid underrun — skip_v weights for species 8,9 were left unwritten).
//
// Phases:
//   k_transpose : transpose per-l linear weights (and per-species skip
//                 weights) into [out][in] layout so lanes read float4 rows.
//   k_up        : s_up = s @ W_up_s /8 ; v_up = v @ W_up_v /8  (v as [n][c][f])
//   k_edge      : radial MLP (thread-per-edge, h in private LDS, scalarized
//                 weight loads) + channelwise TP + atomic scatter to receivers
//   k_post      : linear_down + symmetric contraction + linear_post + skip
//                 (recomputed here from pristine node_feats) + readout
//
// Workspace layout (floats):
//   [0,          N*64)   s_up
//   [N*64,       N*256)  v_up   [n][c][f]
//   [N*256,      N*320)  s_acc  (zeroed each call)
//   [N*320,      N*512)  v_acc  [n][c][f] (zeroed each call)
//   [N*512, +106496)     transposed weights
// Total ~64.4 MB.
// ---------------------------------------------------------------------------

#define NN 32768
#define EE 262144
#define INV8 0.125f                      // 1/sqrt(64)
#define INV_SQRT8 0.35355339059327373f   // 1/sqrt(8)
#define INVZ 0.039528470752104741f       // 1/sqrt(64*10)
#define EPS_C 0.25f
#define RS2 0.70710678118654752f         // 1/sqrt(2)

__global__ __launch_bounds__(256) void k_transpose(
    const float* __restrict__ a0, const float* __restrict__ a1,
    const float* __restrict__ a2, const float* __restrict__ a3,
    const float* __restrict__ a4, const float* __restrict__ a5,
    const float* __restrict__ sks, const float* __restrict__ skv,
    float* __restrict__ dst) {
  int i = blockIdx.x * 256 + threadIdx.x;
  int r = i & 4095, g = r >> 6, f = r & 63;
  if (i < 24576) {
    int m = i >> 12;
    const float* s = (m == 0) ? a0 : (m == 1) ? a1 : (m == 2) ? a2
                   : (m == 3) ? a3 : (m == 4) ? a4 : a5;
    dst[i] = s[f * 64 + g];
  } else {
    int z = (i - 24576) >> 12;
    if (z < 10) dst[i] = sks[(z * 64 + f) * 64 + g];
    else        dst[i] = skv[((z - 10) * 64 + f) * 64 + g];
  }
}

__global__ __launch_bounds__(256) void k_up(
    const float* __restrict__ nf,
    const float* __restrict__ WupsT, const float* __restrict__ WupvT,
    float* __restrict__ s_up, float* __restrict__ v_up) {
  int g = threadIdx.x & 63;
  int wave = blockIdx.x * 4 + (threadIdx.x >> 6);
  int n0 = wave * 4;
  float su[4] = {0.f, 0.f, 0.f, 0.f};
  float vu[4][3] = {{0,0,0},{0,0,0},{0,0,0},{0,0,0}};
  const float4* WsT = (const float4*)(WupsT + g * 64);
  const float4* WvT = (const float4*)(WupvT + g * 64);
  for (int fb = 0; fb < 16; ++fb) {
    float4 ws = WsT[fb];
    float4 wv = WvT[fb];
#pragma unroll
    for (int i = 0; i < 4; ++i) {
      const float* row = nf + (size_t)(n0 + i) * 256;
      float4 s4 = *(const float4*)(row + fb * 4);
      const float4* vr = (const float4*)(row + 64 + fb * 12);
      float4 va = vr[0], vb = vr[1], vc = vr[2];
      // f=4fb+0:(va.x,va.y,va.z) f+1:(va.w,vb.x,vb.y) f+2:(vb.z,vb.w,vc.x) f+3:(vc.y,vc.z,vc.w)
      su[i]    += s4.x * ws.x + s4.y * ws.y + s4.z * ws.z + s4.w * ws.w;
      vu[i][0] += va.x * wv.x + va.w * wv.y + vb.z * wv.z + vc.y * wv.w;
      vu[i][1] += va.y * wv.x + vb.x * wv.y + vb.w * wv.z + vc.z * wv.w;
      vu[i][2] += va.z * wv.x + vb.y * wv.y + vc.x * wv.z + vc.w * wv.w;
    }
  }
#pragma unroll
  for (int i = 0; i < 4; ++i) {
    int n = n0 + i;
    s_up[n * 64 + g] = su[i] * INV8;
    v_up[(n * 3 + 0) * 64 + g] = vu[i][0] * INV8;
    v_up[(n * 3 + 1) * 64 + g] = vu[i][1] * INV8;
    v_up[(n * 3 + 2) * 64 + g] = vu[i][2] * INV8;
  }
}

__device__ __forceinline__ float silu_f(float x) {
  return x / (1.0f + __expf(-x));
}

// thread-per-edge; per-thread private 128-float LDS region (2 ping-pong h
// slots of 64, swizzled (k+t)&63 -> every wave access is 2-lanes/bank = free).
__global__ __launch_bounds__(128) void k_edge(
    const float* __restrict__ vecs, const float* __restrict__ re,
    const float* __restrict__ W1, const float* __restrict__ W2,
    const float* __restrict__ W3, const float* __restrict__ W4,
    const float* __restrict__ s_up, const float* __restrict__ v_up,
    const int* __restrict__ snd, const int* __restrict__ rcv,
    float* __restrict__ s_acc, float* __restrict__ v_acc) {
  __shared__ float h[128 * 128];  // 64 KB
  int t = threadIdx.x;
  int e = blockIdx.x * 128 + t;
  float* hb = h + t * 128;

  float rads[8];
  {
    const float4* rp = (const float4*)(re + (size_t)e * 8);
    float4 r0 = rp[0], r1 = rp[1];
    rads[0] = r0.x; rads[1] = r0.y; rads[2] = r0.z; rads[3] = r0.w;
    rads[4] = r1.x; rads[5] = r1.y; rads[6] = r1.z; rads[7] = r1.w;
  }

  // layer 1 -> slot 0
  for (int jb = 0; jb < 8; ++jb) {
    float acc[8] = {0,0,0,0,0,0,0,0};
#pragma unroll
    for (int r = 0; r < 8; ++r) {
      const float* wr = W1 + r * 64 + jb * 8;  // uniform -> s_load
#pragma unroll
      for (int j = 0; j < 8; ++j) acc[j] += rads[r] * wr[j];
    }
#pragma unroll
    for (int j = 0; j < 8; ++j)
      hb[(jb * 8 + j + t) & 63] = silu_f(acc[j] * INV_SQRT8);
  }

  // layer 2: slot0 -> slot1 ; layer 3: slot1 -> slot0
#pragma unroll 1
  for (int L = 0; L < 2; ++L) {
    const float* W = (L == 0) ? W2 : W3;
    int soff = (L == 0) ? 0 : 64;
    int doff = 64 - soff;
    for (int jb = 0; jb < 8; ++jb) {
      float acc[8] = {0,0,0,0,0,0,0,0};
#pragma unroll 4
      for (int k = 0; k < 64; ++k) {
        float hk = hb[soff + ((k + t) & 63)];
        const float* wr = W + k * 64 + jb * 8;  // uniform -> s_load_dwordx8
#pragma unroll
        for (int j = 0; j < 8; ++j) acc[j] += hk * wr[j];
      }
#pragma unroll
      for (int j = 0; j < 8; ++j)
        hb[doff + ((jb * 8 + j + t) & 63)] = silu_f(acc[j] * INV8);
    }
  }

  // edge geometry + gather pointers
  float ex = vecs[(size_t)e * 3 + 0];
  float ey = vecs[(size_t)e * 3 + 1];
  float ez = vecs[(size_t)e * 3 + 2];
  float rn = 1.0f / (sqrtf(ex * ex + ey * ey + ez * ez) + 1e-9f);
  float Yx = ex * rn, Yy = ey * rn, Yz = ez * rn;
  int se = snd[e], rc = rcv[e];
  const float* srow = s_up + (size_t)se * 64;
  const float* vrow = v_up + (size_t)se * 192;
  float* sa = s_acc + (size_t)rc * 64;
  float* va = v_acc + (size_t)rc * 192;
  const float C = EPS_C * INV8;  // fold 1/sqrt(H) of layer4 + EPS into scatter

  // layer 4 (h3 @ W4, 5 paths x 8 channels per block) fused with TP + scatter
  for (int fb = 0; fb < 8; ++fb) {
    float w[5][8];
#pragma unroll
    for (int p = 0; p < 5; ++p)
#pragma unroll
      for (int j = 0; j < 8; ++j) w[p][j] = 0.0f;
#pragma unroll 2
    for (int k = 0; k < 64; ++k) {
      float hk = hb[(k + t) & 63];
      const float* wr = W4 + k * 320 + fb * 8;  // uniform -> s_load
#pragma unroll
      for (int p = 0; p < 5; ++p)
#pragma unroll
        for (int j = 0; j < 8; ++j) w[p][j] += hk * wr[p * 64 + j];
    }
    float4 s0 = *(const float4*)(srow + fb * 8);
    float4 s1 = *(const float4*)(srow + fb * 8 + 4);
    float4 x0 = *(const float4*)(vrow + fb * 8);
    float4 x1 = *(const float4*)(vrow + fb * 8 + 4);
    float4 y0 = *(const float4*)(vrow + 64 + fb * 8);
    float4 y1 = *(const float4*)(vrow + 64 + fb * 8 + 4);
    float4 z0 = *(const float4*)(vrow + 128 + fb * 8);
    float4 z1 = *(const float4*)(vrow + 128 + fb * 8 + 4);
    float ssv[8] = {s0.x, s0.y, s0.z, s0.w, s1.x, s1.y, s1.z, s1.w};
    float vxv[8] = {x0.x, x0.y, x0.z, x0.w, x1.x, x1.y, x1.z, x1.w};
    float vyv[8] = {y0.x, y0.y, y0.z, y0.w, y1.x, y1.y, y1.z, y1.w};
    float vzv[8] = {z0.x, z0.y, z0.z, z0.w, z1.x, z1.y, z1.z, z1.w};
#pragma unroll
    for (int j = 0; j < 8; ++j) {
      float vvx = vxv[j], vvy = vyv[j], vvz = vzv[j];
      float dt = vvx * Yx + vvy * Yy + vvz * Yz;
      float cx = vvy * Yz - vvz * Yy;
      float cy = vvz * Yx - vvx * Yz;
      float cz = vvx * Yy - vvy * Yx;
      float ms = w[0][j] * ssv[j] + w[3][j] * dt;
      float mx = w[1][j] * Yx + w[2][j] * vvx + w[4][j] * (cx * RS2);
      float my = w[1][j] * Yy + w[2][j] * vvy + w[4][j] * (cy * RS2);
      float mz = w[1][j] * Yz + w[2][j] * vvz + w[4][j] * (cz * RS2);
      atomicAdd(sa + fb * 8 + j, C * ms);
      atomicAdd(va + fb * 8 + j, C * mx);
      atomicAdd(va + 64 + fb * 8 + j, C * my);
      atomicAdd(va + 128 + fb * 8 + j, C * mz);
    }
  }
}

__global__ __launch_bounds__(256) void k_post(
    const float* __restrict__ nf,
    const float* __restrict__ s_acc, const float* __restrict__ v_acc,
    const float* __restrict__ WdnsT, const float* __restrict__ WdnvT,
    const float* __restrict__ WsksT, const float* __restrict__ WskvT,
    const float* __restrict__ Wsc,
    const float* __restrict__ WpssT, const float* __restrict__ WpsvT,
    const float* __restrict__ Wout, const int* __restrict__ species,
    float* __restrict__ out) {
  __shared__ __align__(16) float xch[4][4][4][68];  // [wave][node][s,vx,vy,vz][g]
  int g = threadIdx.x & 63;
  int wv = threadIdx.x >> 6;
  int n0 = (blockIdx.x * 4 + wv) * 4;
  int spec[4];
#pragma unroll
  for (int i = 0; i < 4; ++i) spec[i] = species[n0 + i];
  float s3[4] = {0, 0, 0, 0};
  float v3[4][3] = {{0,0,0},{0,0,0},{0,0,0},{0,0,0}};
  float sks[4] = {0, 0, 0, 0};
  float skv[4][3] = {{0,0,0},{0,0,0},{0,0,0},{0,0,0}};
  const float4* ds_p = (const float4*)(WdnsT + g * 64);
  const float4* dv_p = (const float4*)(WdnvT + g * 64);
  for (int fb = 0; fb < 16; ++fb) {
    float4 ds = ds_p[fb], dv = dv_p[fb];
#pragma unroll
    for (int i = 0; i < 4; ++i) {
      int n = n0 + i;
      float4 sa = *(const float4*)(s_acc + n * 64 + fb * 4);
      float4 vx = *(const float4*)(v_acc + n * 192 + fb * 4);
      float4 vy = *(const float4*)(v_acc + n * 192 + 64 + fb * 4);
      float4 vz = *(const float4*)(v_acc + n * 192 + 128 + fb * 4);
      s3[i]    += sa.x * ds.x + sa.y * ds.y + sa.z * ds.z + sa.w * ds.w;
      v3[i][0] += vx.x * dv.x + vx.y * dv.y + vx.z * dv.z + vx.w * dv.w;
      v3[i][1] += vy.x * dv.x + vy.y * dv.y + vy.z * dv.z + vy.w * dv.w;
      v3[i][2] += vz.x * dv.x + vz.y * dv.y + vz.z * dv.z + vz.w * dv.w;
      float4 ks = *(const float4*)(WsksT + spec[i] * 4096 + g * 64 + fb * 4);
      float4 kv = *(const float4*)(WskvT + spec[i] * 4096 + g * 64 + fb * 4);
      const float* row = nf + (size_t)n * 256;
      float4 s04 = *(const float4*)(row + fb * 4);
      const float4* vr = (const float4*)(row + 64 + fb * 12);
      float4 va = vr[0], vb = vr[1], vc = vr[2];
      sks[i]    += s04.x * ks.x + s04.y * ks.y + s04.z * ks.z + s04.w * ks.w;
      skv[i][0] += va.x * kv.x + va.w * kv.y + vb.z * kv.z + vc.y * kv.w;
      skv[i][1] += va.y * kv.x + vb.x * kv.y + vb.w * kv.z + vc.z * kv.w;
      skv[i][2] += va.z * kv.x + vb.y * kv.y + vc.x * kv.z + vc.w * kv.w;
    }
  }
#pragma unroll
  for (int i = 0; i < 4; ++i) {
    float s = s3[i] * INV8;
    float vx = v3[i][0] * INV8, vy = v3[i][1] * INV8, vz = v3[i][2] * INV8;
    float vn2 = vx * vx + vy * vy + vz * vz;
    const float* wz = Wsc + spec[i] * 576 + g;
    float w0 = wz[0], w1 = wz[64], w2 = wz[128], w3 = wz[192], w4 = wz[256];
    float w5 = wz[320], w6 = wz[384], w7 = wz[448], w8 = wz[512];
    float s_o = w0 * s + w1 * s * s + w2 * vn2 + w3 * s * s * s + w4 * s * vn2;
    float vcm = w5 + w6 * s + w7 * s * s + w8 * vn2;
    xch[wv][i][0][g] = s_o;
    xch[wv][i][1][g] = vcm * vx;
    xch[wv][i][2][g] = vcm * vy;
    xch[wv][i][3][g] = vcm * vz;
  }
  __syncthreads();
  float s4[4] = {0, 0, 0, 0};
  float v4[4][3] = {{0,0,0},{0,0,0},{0,0,0},{0,0,0}};
  const float4* ps_p = (const float4*)(WpssT + g * 64);
  const float4* pv_p = (const float4*)(WpsvT + g * 64);
  for (int gb = 0; gb < 16; ++gb) {
    float4 ps = ps_p[gb], pv = pv_p[gb];
#pragma unroll
    for (int i = 0; i < 4; ++i) {
      float4 so = *(const float4*)(&xch[wv][i][0][gb * 4]);
      float4 u0 = *(const float4*)(&xch[wv][i][1][gb * 4]);
      float4 u1 = *(const float4*)(&xch[wv][i][2][gb * 4]);
      float4 u2 = *(const float4*)(&xch[wv][i][3][gb * 4]);
      s4[i]    += so.x * ps.x + so.y * ps.y + so.z * ps.z + so.w * ps.w;
      v4[i][0] += u0.x * pv.x + u0.y * pv.y + u0.z * pv.z + u0.w * pv.w;
      v4[i][1] += u1.x * pv.x + u1.y * pv.y + u1.z * pv.z + u1.w * pv.w;
      v4[i][2] += u2.x * pv.x + u2.y * pv.y + u2.z * pv.z + u2.w * pv.w;
    }
  }
  float wo = Wout[g];
#pragma unroll
  for (int i = 0; i < 4; ++i) {
    int n = n0 + i;
    float sf = s4[i] * INV8 + sks[i] * INVZ;
    float fx = v4[i][0] * INV8 + skv[i][0] * INVZ;
    float fy = v4[i][1] * INV8 + skv[i][1] * INVZ;
    float fz = v4[i][2] * INV8 + skv[i][2] * INVZ;
    float* orow = out + NN + (size_t)n * 256;
    orow[g] = sf;
    orow[64 + g * 3 + 0] = fx;
    orow[64 + g * 3 + 1] = fy;
    orow[64 + g * 3 + 2] = fz;
    float tsum = sf * wo;
#pragma unroll
    for (int off = 32; off > 0; off >>= 1) tsum += __shfl_down(tsum, off);
    if (g == 0) out[n] = tsum * INV8;
  }
}

extern "C" void kernel_launch(void* const* d_in, const int* in_sizes, int n_in,
                              void* d_out, int out_size, void* d_ws, size_t ws_size,
                              hipStream_t stream) {
  (void)in_sizes; (void)n_in; (void)out_size; (void)ws_size;
  const float* vecs = (const float*)d_in[0];
  const float* nf   = (const float*)d_in[1];
  const float* re   = (const float*)d_in[2];
  const float* Wsks = (const float*)d_in[3];
  const float* Wskv = (const float*)d_in[4];
  const float* Wups = (const float*)d_in[5];
  const float* Wupv = (const float*)d_in[6];
  const float* W1   = (const float*)d_in[7];
  const float* W2   = (const float*)d_in[8];
  const float* W3   = (const float*)d_in[9];
  const float* W4   = (const float*)d_in[10];
  const float* Wdns = (const float*)d_in[11];
  const float* Wdnv = (const float*)d_in[12];
  const float* Wsc  = (const float*)d_in[13];
  const float* Wpss = (const float*)d_in[14];
  const float* Wpsv = (const float*)d_in[15];
  const float* Wout = (const float*)d_in[16];
  const int* species = (const int*)d_in[17];
  const int* snd     = (const int*)d_in[18];
  const int* rcv     = (const int*)d_in[19];

  float* ws = (float*)d_ws;
  float* s_up  = ws;
  float* v_up  = ws + (size_t)NN * 64;
  float* s_acc = ws + (size_t)NN * 256;
  float* v_acc = ws + (size_t)NN * 320;
  float* wT    = ws + (size_t)NN * 512;
  float* WupsT = wT;
  float* WupvT = wT + 4096;
  float* WdnsT = wT + 8192;
  float* WdnvT = wT + 12288;
  float* WpssT = wT + 16384;
  float* WpsvT = wT + 20480;
  float* WsksT = wT + 24576;
  float* WskvT = wT + 65536;

  hipMemsetAsync(s_acc, 0, (size_t)NN * 256 * sizeof(float), stream);
  // 106496 transposed elements total = 416 * 256 exactly
  k_transpose<<<416, 256, 0, stream>>>(Wups, Wupv, Wdns, Wdnv, Wpss, Wpsv,
                                       Wsks, Wskv, wT);
  k_up<<<2048, 256, 0, stream>>>(nf, WupsT, WupvT, s_up, v_up);
  k_edge<<<2048, 128, 0, stream>>>(vecs, re, W1, W2, W3, W4, s_up, v_up,
                                   snd, rcv, s_acc, v_acc);
  k_post<<<2048, 256, 0, stream>>>(nf, s_acc, v_acc, WdnsT, WdnvT, WsksT,
                                   WskvT, Wsc, WpssT, WpsvT, Wout, species,
                                   (float*)d_out);
}

// Round 3
// 1681.078 us; speedup vs baseline: 2.4039x; 2.4039x over previous
//
#include <hip/hip_runtime.h>
#include <math.h>

// ---------------------------------------------------------------------------
// MACE layer, round 3: replace the 67M-atomic scatter (19 G atomics/s ceiling,
// 2.15 GB of 32B atomic RMWs) with message materialization + CSR gather.
//
// Pipeline:
//   memset cnt -> k_transpose -> k_hist -> k_scan -> k_fill -> k_up
//   then 4x { k_edge(chunk) writes m_buf ; k_gather(chunk) accumulates acc }
//   -> k_post
//
// Workspace layout (floats, ~136 MB total):
//   s_up   [N*64]          @ 0
//   v_up   [N*192]         @ 2097152
//   acc    [N*256]         @ 8388608    (s | vx | vy | vz per node)
//   wT     [106496]        @ 16777216
//   row_st [32772 ints]    @ 16883712
//   cursor [32768 ints]    @ 16916484
//   elist  [262144 ints]   @ 16949252
//   m_buf  [65536*256]     @ 17211396   (per-chunk messages, 67 MB)
// ---------------------------------------------------------------------------

#define NN 32768
#define EE 262144
#define EC 65536                         // edges per chunk (4 chunks)
#define INV8 0.125f                      // 1/sqrt(64)
#define INV_SQRT8 0.35355339059327373f   // 1/sqrt(8)
#define INVZ 0.039528470752104741f       // 1/sqrt(64*10)
#define EPS_C 0.25f
#define RS2 0.70710678118654752f         // 1/sqrt(2)

__global__ __launch_bounds__(256) void k_transpose(
    const float* __restrict__ a0, const float* __restrict__ a1,
    const float* __restrict__ a2, const float* __restrict__ a3,
    const float* __restrict__ a4, const float* __restrict__ a5,
    const float* __restrict__ sks, const float* __restrict__ skv,
    float* __restrict__ dst) {
  int i = blockIdx.x * 256 + threadIdx.x;
  int r = i & 4095, g = r >> 6, f = r & 63;
  if (i < 24576) {
    int m = i >> 12;
    const float* s = (m == 0) ? a0 : (m == 1) ? a1 : (m == 2) ? a2
                   : (m == 3) ? a3 : (m == 4) ? a4 : a5;
    dst[i] = s[f * 64 + g];
  } else {
    int z = (i - 24576) >> 12;
    if (z < 10) dst[i] = sks[(z * 64 + f) * 64 + g];
    else        dst[i] = skv[((z - 10) * 64 + f) * 64 + g];
  }
}

__global__ __launch_bounds__(256) void k_hist(const int* __restrict__ rcv,
                                              int* __restrict__ cnt) {
  int e = blockIdx.x * 256 + threadIdx.x;
  atomicAdd(&cnt[rcv[e]], 1);
}

// single-block exclusive scan over 32768 counters -> row_start + cursor copy
__global__ __launch_bounds__(1024) void k_scan(const int* __restrict__ cnt,
                                               int* __restrict__ row_start,
                                               int* __restrict__ cursor) {
  __shared__ int tot[1024];
  int t = threadIdx.x;
  int base = t * 32;
  int local[32];
  int s = 0;
#pragma unroll
  for (int i = 0; i < 32; ++i) { local[i] = s; s += cnt[base + i]; }
  tot[t] = s;
  __syncthreads();
  for (int off = 1; off < 1024; off <<= 1) {
    int v = (t >= off) ? tot[t - off] : 0;
    __syncthreads();
    tot[t] += v;
    __syncthreads();
  }
  int prefix = (t == 0) ? 0 : tot[t - 1];
#pragma unroll
  for (int i = 0; i < 32; ++i) {
    int v = prefix + local[i];
    row_start[base + i] = v;
    cursor[base + i] = v;
  }
  if (t == 1023) row_start[NN] = prefix + s;
}

__global__ __launch_bounds__(256) void k_fill(const int* __restrict__ rcv,
                                              int* __restrict__ cursor,
                                              int* __restrict__ elist) {
  int e = blockIdx.x * 256 + threadIdx.x;
  int pos = atomicAdd(&cursor[rcv[e]], 1);
  elist[pos] = e;
}

__global__ __launch_bounds__(256) void k_up(
    const float* __restrict__ nf,
    const float* __restrict__ WupsT, const float* __restrict__ WupvT,
    float* __restrict__ s_up, float* __restrict__ v_up) {
  int g = threadIdx.x & 63;
  int wave = blockIdx.x * 4 + (threadIdx.x >> 6);
  int n0 = wave * 4;
  float su[4] = {0.f, 0.f, 0.f, 0.f};
  float vu[4][3] = {{0,0,0},{0,0,0},{0,0,0},{0,0,0}};
  const float4* WsT = (const float4*)(WupsT + g * 64);
  const float4* WvT = (const float4*)(WupvT + g * 64);
  for (int fb = 0; fb < 16; ++fb) {
    float4 ws = WsT[fb];
    float4 wv = WvT[fb];
#pragma unroll
    for (int i = 0; i < 4; ++i) {
      const float* row = nf + (size_t)(n0 + i) * 256;
      float4 s4 = *(const float4*)(row + fb * 4);
      const float4* vr = (const float4*)(row + 64 + fb * 12);
      float4 va = vr[0], vb = vr[1], vc = vr[2];
      su[i]    += s4.x * ws.x + s4.y * ws.y + s4.z * ws.z + s4.w * ws.w;
      vu[i][0] += va.x * wv.x + va.w * wv.y + vb.z * wv.z + vc.y * wv.w;
      vu[i][1] += va.y * wv.x + vb.x * wv.y + vb.w * wv.z + vc.z * wv.w;
      vu[i][2] += va.z * wv.x + vb.y * wv.y + vc.x * wv.z + vc.w * wv.w;
    }
  }
#pragma unroll
  for (int i = 0; i < 4; ++i) {
    int n = n0 + i;
    s_up[n * 64 + g] = su[i] * INV8;
    v_up[(n * 3 + 0) * 64 + g] = vu[i][0] * INV8;
    v_up[(n * 3 + 1) * 64 + g] = vu[i][1] * INV8;
    v_up[(n * 3 + 2) * 64 + g] = vu[i][2] * INV8;
  }
}

__device__ __forceinline__ float silu_f(float x) {
  return x / (1.0f + __expf(-x));
}

// thread-per-edge; per-thread private 128-float LDS region (2 ping-pong h
// slots of 64, swizzled (k+t)&63 -> every wave access is 2-lanes/bank = free).
// Writes the 256-float TP message contiguously to m_buf (no atomics).
__global__ __launch_bounds__(128) void k_edge(
    const float* __restrict__ vecs, const float* __restrict__ re,
    const float* __restrict__ W1, const float* __restrict__ W2,
    const float* __restrict__ W3, const float* __restrict__ W4,
    const float* __restrict__ s_up, const float* __restrict__ v_up,
    const int* __restrict__ snd, int e0, float* __restrict__ m_buf) {
  __shared__ float h[128 * 128];  // 64 KB
  int t = threadIdx.x;
  int e = e0 + blockIdx.x * 128 + t;
  float* hb = h + t * 128;

  float rads[8];
  {
    const float4* rp = (const float4*)(re + (size_t)e * 8);
    float4 r0 = rp[0], r1 = rp[1];
    rads[0] = r0.x; rads[1] = r0.y; rads[2] = r0.z; rads[3] = r0.w;
    rads[4] = r1.x; rads[5] = r1.y; rads[6] = r1.z; rads[7] = r1.w;
  }

  // layer 1 -> slot 0
  for (int jb = 0; jb < 8; ++jb) {
    float acc[8] = {0,0,0,0,0,0,0,0};
#pragma unroll
    for (int r = 0; r < 8; ++r) {
      const float* wr = W1 + r * 64 + jb * 8;  // uniform -> s_load
#pragma unroll
      for (int j = 0; j < 8; ++j) acc[j] += rads[r] * wr[j];
    }
#pragma unroll
    for (int j = 0; j < 8; ++j)
      hb[(jb * 8 + j + t) & 63] = silu_f(acc[j] * INV_SQRT8);
  }

  // layer 2: slot0 -> slot1 ; layer 3: slot1 -> slot0
#pragma unroll 1
  for (int L = 0; L < 2; ++L) {
    const float* W = (L == 0) ? W2 : W3;
    int soff = (L == 0) ? 0 : 64;
    int doff = 64 - soff;
    for (int jb = 0; jb < 8; ++jb) {
      float acc[8] = {0,0,0,0,0,0,0,0};
#pragma unroll 4
      for (int k = 0; k < 64; ++k) {
        float hk = hb[soff + ((k + t) & 63)];
        const float* wr = W + k * 64 + jb * 8;  // uniform -> s_load_dwordx8
#pragma unroll
        for (int j = 0; j < 8; ++j) acc[j] += hk * wr[j];
      }
#pragma unroll
      for (int j = 0; j < 8; ++j)
        hb[doff + ((jb * 8 + j + t) & 63)] = silu_f(acc[j] * INV8);
    }
  }

  // edge geometry + gather pointers
  float ex = vecs[(size_t)e * 3 + 0];
  float ey = vecs[(size_t)e * 3 + 1];
  float ez = vecs[(size_t)e * 3 + 2];
  float rn = 1.0f / (sqrtf(ex * ex + ey * ey + ez * ez) + 1e-9f);
  float Yx = ex * rn, Yy = ey * rn, Yz = ez * rn;
  int se = snd[e];
  const float* srow = s_up + (size_t)se * 64;
  const float* vrow = v_up + (size_t)se * 192;
  float* mrow = m_buf + (size_t)(e - e0) * 256;
  const float C = EPS_C * INV8;  // fold 1/sqrt(H) of layer4 + EPS into store

  // layer 4 (h3 @ W4, 5 paths x 8 channels per block) fused with TP + store
  for (int fb = 0; fb < 8; ++fb) {
    float w[5][8];
#pragma unroll
    for (int p = 0; p < 5; ++p)
#pragma unroll
      for (int j = 0; j < 8; ++j) w[p][j] = 0.0f;
#pragma unroll 2
    for (int k = 0; k < 64; ++k) {
      float hk = hb[(k + t) & 63];
      const float* wr = W4 + k * 320 + fb * 8;  // uniform -> s_load
#pragma unroll
      for (int p = 0; p < 5; ++p)
#pragma unroll
        for (int j = 0; j < 8; ++j) w[p][j] += hk * wr[p * 64 + j];
    }
    float4 s0 = *(const float4*)(srow + fb * 8);
    float4 s1 = *(const float4*)(srow + fb * 8 + 4);
    float4 x0 = *(const float4*)(vrow + fb * 8);
    float4 x1 = *(const float4*)(vrow + fb * 8 + 4);
    float4 y0 = *(const float4*)(vrow + 64 + fb * 8);
    float4 y1 = *(const float4*)(vrow + 64 + fb * 8 + 4);
    float4 z0 = *(const float4*)(vrow + 128 + fb * 8);
    float4 z1 = *(const float4*)(vrow + 128 + fb * 8 + 4);
    float ssv[8] = {s0.x, s0.y, s0.z, s0.w, s1.x, s1.y, s1.z, s1.w};
    float vxv[8] = {x0.x, x0.y, x0.z, x0.w, x1.x, x1.y, x1.z, x1.w};
    float vyv[8] = {y0.x, y0.y, y0.z, y0.w, y1.x, y1.y, y1.z, y1.w};
    float vzv[8] = {z0.x, z0.y, z0.z, z0.w, z1.x, z1.y, z1.z, z1.w};
    float ms[8], mx[8], my[8], mz[8];
#pragma unroll
    for (int j = 0; j < 8; ++j) {
      float vvx = vxv[j], vvy = vyv[j], vvz = vzv[j];
      float dt = vvx * Yx + vvy * Yy + vvz * Yz;
      float cx = vvy * Yz - vvz * Yy;
      float cy = vvz * Yx - vvx * Yz;
      float cz = vvx * Yy - vvy * Yx;
      ms[j] = C * (w[0][j] * ssv[j] + w[3][j] * dt);
      mx[j] = C * (w[1][j] * Yx + w[2][j] * vvx + w[4][j] * (cx * RS2));
      my[j] = C * (w[1][j] * Yy + w[2][j] * vvy + w[4][j] * (cy * RS2));
      mz[j] = C * (w[1][j] * Yz + w[2][j] * vvz + w[4][j] * (cz * RS2));
    }
    ((float4*)(mrow + fb * 8))[0]       = make_float4(ms[0], ms[1], ms[2], ms[3]);
    ((float4*)(mrow + fb * 8))[1]       = make_float4(ms[4], ms[5], ms[6], ms[7]);
    ((float4*)(mrow + 64 + fb * 8))[0]  = make_float4(mx[0], mx[1], mx[2], mx[3]);
    ((float4*)(mrow + 64 + fb * 8))[1]  = make_float4(mx[4], mx[5], mx[6], mx[7]);
    ((float4*)(mrow + 128 + fb * 8))[0] = make_float4(my[0], my[1], my[2], my[3]);
    ((float4*)(mrow + 128 + fb * 8))[1] = make_float4(my[4], my[5], my[6], my[7]);
    ((float4*)(mrow + 192 + fb * 8))[0] = make_float4(mz[0], mz[1], mz[2], mz[3]);
    ((float4*)(mrow + 192 + fb * 8))[1] = make_float4(mz[4], mz[5], mz[6], mz[7]);
  }
}

// one wave per node; lane g accumulates floats [4g,4g+4) of each incoming
// message in this chunk. Single writer per node -> plain read-modify-write.
__global__ __launch_bounds__(256) void k_gather(
    const float* __restrict__ m_buf, const int* __restrict__ row_start,
    const int* __restrict__ elist, float* __restrict__ acc,
    int e0, int first) {
  int g = threadIdx.x & 63;
  int wv = threadIdx.x >> 6;
  int n = blockIdx.x * 4 + wv;
  int beg = row_start[n], end = row_start[n + 1];
  float4 a = make_float4(0.f, 0.f, 0.f, 0.f);
  for (int i = beg; i < end; ++i) {
    int e = elist[i] - e0;
    if ((unsigned)e < (unsigned)EC) {
      float4 m = *(const float4*)(m_buf + (size_t)e * 256 + g * 4);
      a.x += m.x; a.y += m.y; a.z += m.z; a.w += m.w;
    }
  }
  float* dst = acc + (size_t)n * 256 + g * 4;
  if (!first) {
    float4 p = *(const float4*)dst;
    a.x += p.x; a.y += p.y; a.z += p.z; a.w += p.w;
  }
  *(float4*)dst = a;
}

__global__ __launch_bounds__(256) void k_post(
    const float* __restrict__ nf, const float* __restrict__ acc,
    const float* __restrict__ WdnsT, const float* __restrict__ WdnvT,
    const float* __restrict__ WsksT, const float* __restrict__ WskvT,
    const float* __restrict__ Wsc,
    const float* __restrict__ WpssT, const float* __restrict__ WpsvT,
    const float* __restrict__ Wout, const int* __restrict__ species,
    float* __restrict__ out) {
  __shared__ __align__(16) float xch[4][4][4][68];  // [wave][node][s,vx,vy,vz][g]
  int g = threadIdx.x & 63;
  int wv = threadIdx.x >> 6;
  int n0 = (blockIdx.x * 4 + wv) * 4;
  int spec[4];
#pragma unroll
  for (int i = 0; i < 4; ++i) spec[i] = species[n0 + i];
  float s3[4] = {0, 0, 0, 0};
  float v3[4][3] = {{0,0,0},{0,0,0},{0,0,0},{0,0,0}};
  float sks[4] = {0, 0, 0, 0};
  float skv[4][3] = {{0,0,0},{0,0,0},{0,0,0},{0,0,0}};
  const float4* ds_p = (const float4*)(WdnsT + g * 64);
  const float4* dv_p = (const float4*)(WdnvT + g * 64);
  for (int fb = 0; fb < 16; ++fb) {
    float4 ds = ds_p[fb], dv = dv_p[fb];
#pragma unroll
    for (int i = 0; i < 4; ++i) {
      int n = n0 + i;
      const float* arow = acc + (size_t)n * 256;
      float4 sa = *(const float4*)(arow + fb * 4);
      float4 vx = *(const float4*)(arow + 64 + fb * 4);
      float4 vy = *(const float4*)(arow + 128 + fb * 4);
      float4 vz = *(const float4*)(arow + 192 + fb * 4);
      s3[i]    += sa.x * ds.x + sa.y * ds.y + sa.z * ds.z + sa.w * ds.w;
      v3[i][0] += vx.x * dv.x + vx.y * dv.y + vx.z * dv.z + vx.w * dv.w;
      v3[i][1] += vy.x * dv.x + vy.y * dv.y + vy.z * dv.z + vy.w * dv.w;
      v3[i][2] += vz.x * dv.x + vz.y * dv.y + vz.z * dv.z + vz.w * dv.w;
      float4 ks = *(const float4*)(WsksT + spec[i] * 4096 + g * 64 + fb * 4);
      float4 kv = *(const float4*)(WskvT + spec[i] * 4096 + g * 64 + fb * 4);
      const float* row = nf + (size_t)n * 256;
      float4 s04 = *(const float4*)(row + fb * 4);
      const float4* vr = (const float4*)(row + 64 + fb * 12);
      float4 va = vr[0], vb = vr[1], vc = vr[2];
      sks[i]    += s04.x * ks.x + s04.y * ks.y + s04.z * ks.z + s04.w * ks.w;
      skv[i][0] += va.x * kv.x + va.w * kv.y + vb.z * kv.z + vc.y * kv.w;
      skv[i][1] += va.y * kv.x + vb.x * kv.y + vb.w * kv.z + vc.z * kv.w;
      skv[i][2] += va.z * kv.x + vb.y * kv.y + vc.x * kv.z + vc.w * kv.w;
    }
  }
#pragma unroll
  for (int i = 0; i < 4; ++i) {
    float s = s3[i] * INV8;
    float vx = v3[i][0] * INV8, vy = v3[i][1] * INV8, vz = v3[i][2] * INV8;
    float vn2 = vx * vx + vy * vy + vz * vz;
    const float* wz = Wsc + spec[i] * 576 + g;
    float w0 = wz[0], w1 = wz[64], w2 = wz[128], w3 = wz[192], w4 = wz[256];
    float w5 = wz[320], w6 = wz[384], w7 = wz[448], w8 = wz[512];
    float s_o = w0 * s + w1 * s * s + w2 * vn2 + w3 * s * s * s + w4 * s * vn2;
    float vcm = w5 + w6 * s + w7 * s * s + w8 * vn2;
    xch[wv][i][0][g] = s_o;
    xch[wv][i][1][g] = vcm * vx;
    xch[wv][i][2][g] = vcm * vy;
    xch[wv][i][3][g] = vcm * vz;
  }
  __syncthreads();
  float s4[4] = {0, 0, 0, 0};
  float v4[4][3] = {{0,0,0},{0,0,0},{0,0,0},{0,0,0}};
  const float4* ps_p = (const float4*)(WpssT + g * 64);
  const float4* pv_p = (const float4*)(WpsvT + g * 64);
  for (int gb = 0; gb < 16; ++gb) {
    float4 ps = ps_p[gb], pv = pv_p[gb];
#pragma unroll
    for (int i = 0; i < 4; ++i) {
      float4 so = *(const float4*)(&xch[wv][i][0][gb * 4]);
      float4 u0 = *(const float4*)(&xch[wv][i][1][gb * 4]);
      float4 u1 = *(const float4*)(&xch[wv][i][2][gb * 4]);
      float4 u2 = *(const float4*)(&xch[wv][i][3][gb * 4]);
      s4[i]    += so.x * ps.x + so.y * ps.y + so.z * ps.z + so.w * ps.w;
      v4[i][0] += u0.x * pv.x + u0.y * pv.y + u0.z * pv.z + u0.w * pv.w;
      v4[i][1] += u1.x * pv.x + u1.y * pv.y + u1.z * pv.z + u1.w * pv.w;
      v4[i][2] += u2.x * pv.x + u2.y * pv.y + u2.z * pv.z + u2.w * pv.w;
    }
  }
  float wo = Wout[g];
#pragma unroll
  for (int i = 0; i < 4; ++i) {
    int n = n0 + i;
    float sf = s4[i] * INV8 + sks[i] * INVZ;
    float fx = v4[i][0] * INV8 + skv[i][0] * INVZ;
    float fy = v4[i][1] * INV8 + skv[i][1] * INVZ;
    float fz = v4[i][2] * INV8 + skv[i][2] * INVZ;
    float* orow = out + NN + (size_t)n * 256;
    orow[g] = sf;
    orow[64 + g * 3 + 0] = fx;
    orow[64 + g * 3 + 1] = fy;
    orow[64 + g * 3 + 2] = fz;
    float tsum = sf * wo;
#pragma unroll
    for (int off = 32; off > 0; off >>= 1) tsum += __shfl_down(tsum, off);
    if (g == 0) out[n] = tsum * INV8;
  }
}

extern "C" void kernel_launch(void* const* d_in, const int* in_sizes, int n_in,
                              void* d_out, int out_size, void* d_ws, size_t ws_size,
                              hipStream_t stream) {
  (void)in_sizes; (void)n_in; (void)out_size; (void)ws_size;
  const float* vecs = (const float*)d_in[0];
  const float* nf   = (const float*)d_in[1];
  const float* re   = (const float*)d_in[2];
  const float* Wsks = (const float*)d_in[3];
  const float* Wskv = (const float*)d_in[4];
  const float* Wups = (const float*)d_in[5];
  const float* Wupv = (const float*)d_in[6];
  const float* W1   = (const float*)d_in[7];
  const float* W2   = (const float*)d_in[8];
  const float* W3   = (const float*)d_in[9];
  const float* W4   = (const float*)d_in[10];
  const float* Wdns = (const float*)d_in[11];
  const float* Wdnv = (const float*)d_in[12];
  const float* Wsc  = (const float*)d_in[13];
  const float* Wpss = (const float*)d_in[14];
  const float* Wpsv = (const float*)d_in[15];
  const float* Wout = (const float*)d_in[16];
  const int* species = (const int*)d_in[17];
  const int* snd     = (const int*)d_in[18];
  const int* rcv     = (const int*)d_in[19];

  float* ws = (float*)d_ws;
  float* s_up  = ws;                               // N*64
  float* v_up  = ws + 2097152;                     // N*192
  float* acc   = ws + 8388608;                     // N*256
  float* wT    = ws + 16777216;                    // 106496
  int* row_st  = (int*)(ws + 16883712);            // 32769 (+pad)
  int* cursor  = (int*)(ws + 16916484);            // 32768
  int* elist   = (int*)(ws + 16949252);            // 262144
  float* m_buf = ws + 17211396;                    // EC*256 = 16777216

  float* WupsT = wT;
  float* WupvT = wT + 4096;
  float* WdnsT = wT + 8192;
  float* WdnvT = wT + 12288;
  float* WpssT = wT + 16384;
  float* WpsvT = wT + 20480;
  float* WsksT = wT + 24576;
  float* WskvT = wT + 65536;

  hipMemsetAsync(cursor, 0, NN * sizeof(int), stream);
  k_transpose<<<416, 256, 0, stream>>>(Wups, Wupv, Wdns, Wdnv, Wpss, Wpsv,
                                       Wsks, Wskv, wT);
  k_hist<<<EE / 256, 256, 0, stream>>>(rcv, cursor);
  k_scan<<<1, 1024, 0, stream>>>(cursor, row_st, cursor);
  k_fill<<<EE / 256, 256, 0, stream>>>(rcv, cursor, elist);
  k_up<<<2048, 256, 0, stream>>>(nf, WupsT, WupvT, s_up, v_up);
  for (int c = 0; c < 4; ++c) {
    k_edge<<<EC / 128, 128, 0, stream>>>(vecs, re, W1, W2, W3, W4, s_up, v_up,
                                         snd, c * EC, m_buf);
    k_gather<<<NN / 4, 256, 0, stream>>>(m_buf, row_st, elist, acc,
                                         c * EC, c == 0);
  }
  k_post<<<2048, 256, 0, stream>>>(nf, acc, WdnsT, WdnvT, WsksT,
                                   WskvT, Wsc, WpssT, WpsvT, Wout, species,
                                   (float*)d_out);
}

// Round 4
// 1609.125 us; speedup vs baseline: 2.5114x; 1.0447x over previous
//
#include <hip/hip_runtime.h>
#include <math.h>

// ---------------------------------------------------------------------------
// MACE layer, round 4.
//  - k_post/k_up: weights in ORIGINAL [f][g] layout -> lane-g coalesced reads
//    (round-3's transposed layout caused 64-line/instr uncoalesced gathers).
//  - k_edge: CSR-ordered edges, register-resident MLP (h1,h3 regs; h2 in
//    64-float/thread swizzled LDS), s_load weights, no barriers, no atomics.
//  - k_gather: contiguous clipped CSR range per chunk.
//
// Workspace layout (floats, ~136 MB):
//   s_up   [N*64]        @ 0
//   v_up   [N*192]       @ 2097152
//   acc    [N*256]       @ 8388608   (zeroed per call)
//   wT     [8704]        @ 16777216  (W1T 512 | W2T 4096 | W3T 4096)
//   row_st [32772 ints]  @ 16785920
//   cursor [32768 ints]  @ 16818692
//   elist  [262144 ints] @ 16851460
//   m_buf  [EC*256]      @ 17113604  (67 MB, float4-aligned)
// ---------------------------------------------------------------------------

#define NN 32768
#define EE 262144
#define EC 65536                         // edges per chunk (4 chunks)
#define INV8 0.125f                      // 1/sqrt(64)
#define INV_SQRT8 0.35355339059327373f   // 1/sqrt(8)
#define INVZ 0.039528470752104741f       // 1/sqrt(64*10)
#define EPS_C 0.25f
#define RS2 0.70710678118654752f         // 1/sqrt(2)

// Transpose only the MLP weights needed for wave-uniform s_load rows.
__global__ __launch_bounds__(256) void k_wt(
    const float* __restrict__ W1, const float* __restrict__ W2,
    const float* __restrict__ W3, float* __restrict__ dst) {
  int i = blockIdx.x * 256 + threadIdx.x;  // 8704 total
  if (i < 512) {
    dst[i] = W1[(i & 7) * 64 + (i >> 3)];          // W1T[j][r]
  } else if (i < 4608) {
    int i2 = i - 512;
    dst[i] = W2[(i2 & 63) * 64 + (i2 >> 6)];       // W2T[j][k]
  } else {
    int i3 = i - 4608;
    dst[i] = W3[(i3 & 63) * 64 + (i3 >> 6)];       // W3T[j][k]
  }
}

__global__ __launch_bounds__(256) void k_hist(const int* __restrict__ rcv,
                                              int* __restrict__ cnt) {
  int e = blockIdx.x * 256 + threadIdx.x;
  atomicAdd(&cnt[rcv[e]], 1);
}

__global__ __launch_bounds__(1024) void k_scan(const int* __restrict__ cnt,
                                               int* __restrict__ row_start,
                                               int* __restrict__ cursor) {
  __shared__ int tot[1024];
  int t = threadIdx.x;
  int base = t * 32;
  int local[32];
  int s = 0;
#pragma unroll
  for (int i = 0; i < 32; ++i) { local[i] = s; s += cnt[base + i]; }
  tot[t] = s;
  __syncthreads();
  for (int off = 1; off < 1024; off <<= 1) {
    int v = (t >= off) ? tot[t - off] : 0;
    __syncthreads();
    tot[t] += v;
    __syncthreads();
  }
  int prefix = (t == 0) ? 0 : tot[t - 1];
#pragma unroll
  for (int i = 0; i < 32; ++i) {
    int v = prefix + local[i];
    row_start[base + i] = v;
    cursor[base + i] = v;
  }
  if (t == 1023) row_start[NN] = prefix + s;
}

__global__ __launch_bounds__(256) void k_fill(const int* __restrict__ rcv,
                                              int* __restrict__ cursor,
                                              int* __restrict__ elist) {
  int e = blockIdx.x * 256 + threadIdx.x;
  int pos = atomicAdd(&cursor[rcv[e]], 1);
  elist[pos] = e;
}

// linear_up: lane g = output channel; weights original layout -> coalesced;
// node data broadcast. 4 nodes per wave.
__global__ __launch_bounds__(256) void k_up(
    const float* __restrict__ nf,
    const float* __restrict__ Wups, const float* __restrict__ Wupv,
    float* __restrict__ s_up, float* __restrict__ v_up) {
  int g = threadIdx.x & 63;
  int n0 = (blockIdx.x * 4 + (threadIdx.x >> 6)) * 4;
  float su[4] = {0.f, 0.f, 0.f, 0.f};
  float vu[4][3] = {{0,0,0},{0,0,0},{0,0,0},{0,0,0}};
  for (int fq = 0; fq < 16; ++fq) {
    int f = fq * 4;
    float ws0 = Wups[(f + 0) * 64 + g], ws1 = Wups[(f + 1) * 64 + g];
    float ws2 = Wups[(f + 2) * 64 + g], ws3 = Wups[(f + 3) * 64 + g];
    float wv0 = Wupv[(f + 0) * 64 + g], wv1 = Wupv[(f + 1) * 64 + g];
    float wv2 = Wupv[(f + 2) * 64 + g], wv3 = Wupv[(f + 3) * 64 + g];
#pragma unroll
    for (int i = 0; i < 4; ++i) {
      const float* row = nf + (size_t)(n0 + i) * 256;
      float4 s4 = *(const float4*)(row + f);
      const float4* vr = (const float4*)(row + 64 + fq * 12);
      float4 va = vr[0], vb = vr[1], vc = vr[2];
      su[i]    += s4.x * ws0 + s4.y * ws1 + s4.z * ws2 + s4.w * ws3;
      vu[i][0] += va.x * wv0 + va.w * wv1 + vb.z * wv2 + vc.y * wv3;
      vu[i][1] += va.y * wv0 + vb.x * wv1 + vb.w * wv2 + vc.z * wv3;
      vu[i][2] += va.z * wv0 + vb.y * wv1 + vc.x * wv2 + vc.w * wv3;
    }
  }
#pragma unroll
  for (int i = 0; i < 4; ++i) {
    int n = n0 + i;
    s_up[n * 64 + g] = su[i] * INV8;
    v_up[(n * 3 + 0) * 64 + g] = vu[i][0] * INV8;
    v_up[(n * 3 + 1) * 64 + g] = vu[i][1] * INV8;
    v_up[(n * 3 + 2) * 64 + g] = vu[i][2] * INV8;
  }
}

__device__ __forceinline__ float silu_f(float x) {
  return x / (1.0f + __expf(-x));
}

// thread-per-edge in CSR order. h1 regs -> h2 LDS (64 f/thread, swizzled,
// conflict-free) -> h3 regs -> layer4+TP. Weights via wave-uniform s_load.
__global__ __launch_bounds__(128) void k_edge(
    const float* __restrict__ vecs, const float* __restrict__ re,
    const float* __restrict__ W1T, const float* __restrict__ W2T,
    const float* __restrict__ W3T, const float* __restrict__ W4,
    const float* __restrict__ s_up, const float* __restrict__ v_up,
    const int* __restrict__ snd, const int* __restrict__ elist,
    int e0, float* __restrict__ m_buf) {
  __shared__ float lh[128 * 64];  // 32 KB
  int t = threadIdx.x;
  int ip = blockIdx.x * 128 + t;       // chunk-local CSR position
  int e = elist[e0 + ip];
  float* hb = lh + t * 64;

  float r8[8];
  {
    const float4* rp = (const float4*)(re + (size_t)e * 8);
    float4 ra = rp[0], rb = rp[1];
    r8[0] = ra.x; r8[1] = ra.y; r8[2] = ra.z; r8[3] = ra.w;
    r8[4] = rb.x; r8[5] = rb.y; r8[6] = rb.z; r8[7] = rb.w;
  }

  // layer 1 -> h1 registers
  float h1[64];
#pragma unroll
  for (int j = 0; j < 64; ++j) {
    const float* w = W1T + j * 8;      // uniform -> s_load
    float a = 0.f;
#pragma unroll
    for (int r = 0; r < 8; ++r) a += r8[r] * w[r];
    h1[j] = silu_f(a * INV_SQRT8);
  }

  // layer 2: h1 regs -> h2 LDS (swizzled (j+t)&63: 2 lanes/bank = free)
#pragma unroll 1
  for (int j = 0; j < 64; ++j) {
    const float* w = W2T + j * 64;     // uniform -> s_load rows
    float a = 0.f;
#pragma unroll
    for (int k = 0; k < 64; ++k) a += h1[k] * w[k];
    hb[(j + t) & 63] = silu_f(a * INV8);
  }

  // layer 3: h2 LDS -> h3 regs (g8 unrolled so h3 index is static;
  // k16 rolled with 16-value LDS cache to bound code size / registers)
  float h3[64];
#pragma unroll
  for (int g8 = 0; g8 < 8; ++g8) {
    float a8[8] = {0, 0, 0, 0, 0, 0, 0, 0};
#pragma unroll 1
    for (int k16 = 0; k16 < 4; ++k16) {
      float hc[16];
#pragma unroll
      for (int k = 0; k < 16; ++k) hc[k] = hb[(k16 * 16 + k + t) & 63];
#pragma unroll
      for (int jj = 0; jj < 8; ++jj) {
        const float* w = W3T + (g8 * 8 + jj) * 64 + k16 * 16;  // uniform
        float a = 0.f;
#pragma unroll
        for (int k = 0; k < 16; ++k) a += hc[k] * w[k];
        a8[jj] += a;
      }
    }
#pragma unroll
    for (int jj = 0; jj < 8; ++jj)
      h3[g8 * 8 + jj] = silu_f(a8[jj] * INV8);
  }

  // edge geometry + gather pointers
  float ex = vecs[(size_t)e * 3 + 0];
  float ey = vecs[(size_t)e * 3 + 1];
  float ez = vecs[(size_t)e * 3 + 2];
  float rn = 1.0f / (sqrtf(ex * ex + ey * ey + ez * ez) + 1e-9f);
  float Yx = ex * rn, Yy = ey * rn, Yz = ez * rn;
  int se = snd[e];
  const float* srow = s_up + (size_t)se * 64;
  const float* vrow = v_up + (size_t)se * 192;
  float* mrow = m_buf + (size_t)ip * 256;
  const float C = EPS_C * INV8;  // fold layer4 1/sqrt(H) + EPS into store

  // layer 4 (h3 @ W4) fused with TP + contiguous message store
#pragma unroll 1
  for (int fb = 0; fb < 8; ++fb) {
    float w[5][8];
#pragma unroll
    for (int p = 0; p < 5; ++p)
#pragma unroll
      for (int j = 0; j < 8; ++j) w[p][j] = 0.0f;
#pragma unroll
    for (int k = 0; k < 64; ++k) {
      const float* wr = W4 + k * 320 + fb * 8;  // uniform -> s_load_dwordx8
      float hk = h3[k];
#pragma unroll
      for (int p = 0; p < 5; ++p)
#pragma unroll
        for (int j = 0; j < 8; ++j) w[p][j] += hk * wr[p * 64 + j];
    }
    float4 s0 = *(const float4*)(srow + fb * 8);
    float4 s1 = *(const float4*)(srow + fb * 8 + 4);
    float4 x0 = *(const float4*)(vrow + fb * 8);
    float4 x1 = *(const float4*)(vrow + fb * 8 + 4);
    float4 y0 = *(const float4*)(vrow + 64 + fb * 8);
    float4 y1 = *(const float4*)(vrow + 64 + fb * 8 + 4);
    float4 z0 = *(const float4*)(vrow + 128 + fb * 8);
    float4 z1 = *(const float4*)(vrow + 128 + fb * 8 + 4);
    float ssv[8] = {s0.x, s0.y, s0.z, s0.w, s1.x, s1.y, s1.z, s1.w};
    float vxv[8] = {x0.x, x0.y, x0.z, x0.w, x1.x, x1.y, x1.z, x1.w};
    float vyv[8] = {y0.x, y0.y, y0.z, y0.w, y1.x, y1.y, y1.z, y1.w};
    float vzv[8] = {z0.x, z0.y, z0.z, z0.w, z1.x, z1.y, z1.z, z1.w};
    float ms[8], mx[8], my[8], mz[8];
#pragma unroll
    for (int j = 0; j < 8; ++j) {
      float vvx = vxv[j], vvy = vyv[j], vvz = vzv[j];
      float dt = vvx * Yx + vvy * Yy + vvz * Yz;
      float cx = vvy * Yz - vvz * Yy;
      float cy = vvz * Yx - vvx * Yz;
      float cz = vvx * Yy - vvy * Yx;
      ms[j] = C * (w[0][j] * ssv[j] + w[3][j] * dt);
      mx[j] = C * (w[1][j] * Yx + w[2][j] * vvx + w[4][j] * (cx * RS2));
      my[j] = C * (w[1][j] * Yy + w[2][j] * vvy + w[4][j] * (cy * RS2));
      mz[j] = C * (w[1][j] * Yz + w[2][j] * vvz + w[4][j] * (cz * RS2));
    }
    ((float4*)(mrow + fb * 8))[0]       = make_float4(ms[0], ms[1], ms[2], ms[3]);
    ((float4*)(mrow + fb * 8))[1]       = make_float4(ms[4], ms[5], ms[6], ms[7]);
    ((float4*)(mrow + 64 + fb * 8))[0]  = make_float4(mx[0], mx[1], mx[2], mx[3]);
    ((float4*)(mrow + 64 + fb * 8))[1]  = make_float4(mx[4], mx[5], mx[6], mx[7]);
    ((float4*)(mrow + 128 + fb * 8))[0] = make_float4(my[0], my[1], my[2], my[3]);
    ((float4*)(mrow + 128 + fb * 8))[1] = make_float4(my[4], my[5], my[6], my[7]);
    ((float4*)(mrow + 192 + fb * 8))[0] = make_float4(mz[0], mz[1], mz[2], mz[3]);
    ((float4*)(mrow + 192 + fb * 8))[1] = make_float4(mz[4], mz[5], mz[6], mz[7]);
  }
}

// one wave per node; contiguous clipped CSR range [lo,hi) of this chunk.
__global__ __launch_bounds__(256) void k_gather(
    const float* __restrict__ m_buf, const int* __restrict__ row_start,
    float* __restrict__ acc, int e0, int e1) {
  int g = threadIdx.x & 63;
  int wv = threadIdx.x >> 6;
  int n = blockIdx.x * 4 + wv;
  int beg = row_start[n], end = row_start[n + 1];
  int lo = beg > e0 ? beg : e0;
  int hi = end < e1 ? end : e1;
  if (lo >= hi) return;
  float4 a = make_float4(0.f, 0.f, 0.f, 0.f);
  for (int i = lo; i < hi; ++i) {
    float4 m = *(const float4*)(m_buf + (size_t)(i - e0) * 256 + g * 4);
    a.x += m.x; a.y += m.y; a.z += m.z; a.w += m.w;
  }
  float* dst = acc + (size_t)n * 256 + g * 4;
  float4 p = *(const float4*)dst;  // serialized chunks: RMW is safe
  *(float4*)dst = make_float4(a.x + p.x, a.y + p.y, a.z + p.z, a.w + p.w);
}

__global__ __launch_bounds__(256) void k_post(
    const float* __restrict__ nf, const float* __restrict__ acc,
    const float* __restrict__ Wdns, const float* __restrict__ Wdnv,
    const float* __restrict__ Wsks, const float* __restrict__ Wskv,
    const float* __restrict__ Wsc,
    const float* __restrict__ Wpss, const float* __restrict__ Wpsv,
    const float* __restrict__ Wout, const int* __restrict__ species,
    float* __restrict__ out) {
  __shared__ __align__(16) float xch[4][4][4][68];
  int g = threadIdx.x & 63;
  int wv = threadIdx.x >> 6;
  int n0 = (blockIdx.x * 4 + wv) * 4;
  int spec[4];
#pragma unroll
  for (int i = 0; i < 4; ++i) spec[i] = species[n0 + i];
  float s3[4] = {0, 0, 0, 0};
  float v3[4][3] = {{0,0,0},{0,0,0},{0,0,0},{0,0,0}};
  float sks[4] = {0, 0, 0, 0};
  float skv[4][3] = {{0,0,0},{0,0,0},{0,0,0},{0,0,0}};
  for (int fq = 0; fq < 16; ++fq) {
    int f = fq * 4;
    float d0 = Wdns[(f + 0) * 64 + g], d1 = Wdns[(f + 1) * 64 + g];
    float d2 = Wdns[(f + 2) * 64 + g], d3 = Wdns[(f + 3) * 64 + g];
    float e0 = Wdnv[(f + 0) * 64 + g], e1 = Wdnv[(f + 1) * 64 + g];
    float e2 = Wdnv[(f + 2) * 64 + g], e3 = Wdnv[(f + 3) * 64 + g];
#pragma unroll
    for (int i = 0; i < 4; ++i) {
      int n = n0 + i;
      const float* arow = acc + (size_t)n * 256;
      float4 sa = *(const float4*)(arow + f);
      float4 vx = *(const float4*)(arow + 64 + f);
      float4 vy = *(const float4*)(arow + 128 + f);
      float4 vz = *(const float4*)(arow + 192 + f);
      s3[i]    += sa.x * d0 + sa.y * d1 + sa.z * d2 + sa.w * d3;
      v3[i][0] += vx.x * e0 + vx.y * e1 + vx.z * e2 + vx.w * e3;
      v3[i][1] += vy.x * e0 + vy.y * e1 + vy.z * e2 + vy.w * e3;
      v3[i][2] += vz.x * e0 + vz.y * e1 + vz.z * e2 + vz.w * e3;
      const float* ksb = Wsks + spec[i] * 4096 + f * 64 + g;  // coalesced
      const float* kvb = Wskv + spec[i] * 4096 + f * 64 + g;
      float k0 = ksb[0], k1 = ksb[64], k2 = ksb[128], k3 = ksb[192];
      float q0 = kvb[0], q1 = kvb[64], q2 = kvb[128], q3 = kvb[192];
      const float* row = nf + (size_t)n * 256;
      float4 s04 = *(const float4*)(row + f);
      const float4* vr = (const float4*)(row + 64 + fq * 12);
      float4 va = vr[0], vb = vr[1], vc = vr[2];
      sks[i]    += s04.x * k0 + s04.y * k1 + s04.z * k2 + s04.w * k3;
      skv[i][0] += va.x * q0 + va.w * q1 + vb.z * q2 + vc.y * q3;
      skv[i][1] += va.y * q0 + vb.x * q1 + vb.w * q2 + vc.z * q3;
      skv[i][2] += va.z * q0 + vb.y * q1 + vc.x * q2 + vc.w * q3;
    }
  }
#pragma unroll
  for (int i = 0; i < 4; ++i) {
    float s = s3[i] * INV8;
    float vx = v3[i][0] * INV8, vy = v3[i][1] * INV8, vz = v3[i][2] * INV8;
    float vn2 = vx * vx + vy * vy + vz * vz;
    const float* wz = Wsc + spec[i] * 576 + g;
    float w0 = wz[0], w1 = wz[64], w2 = wz[128], w3 = wz[192], w4 = wz[256];
    float w5 = wz[320], w6 = wz[384], w7 = wz[448], w8 = wz[512];
    float s_o = w0 * s + w1 * s * s + w2 * vn2 + w3 * s * s * s + w4 * s * vn2;
    float vcm = w5 + w6 * s + w7 * s * s + w8 * vn2;
    xch[wv][i][0][g] = s_o;
    xch[wv][i][1][g] = vcm * vx;
    xch[wv][i][2][g] = vcm * vy;
    xch[wv][i][3][g] = vcm * vz;
  }
  __syncthreads();
  float s4[4] = {0, 0, 0, 0};
  float v4[4][3] = {{0,0,0},{0,0,0},{0,0,0},{0,0,0}};
  for (int fq = 0; fq < 16; ++fq) {
    int f = fq * 4;
    float p0 = Wpss[(f + 0) * 64 + g], p1 = Wpss[(f + 1) * 64 + g];
    float p2 = Wpss[(f + 2) * 64 + g], p3 = Wpss[(f + 3) * 64 + g];
    float q0 = Wpsv[(f + 0) * 64 + g], q1 = Wpsv[(f + 1) * 64 + g];
    float q2 = Wpsv[(f + 2) * 64 + g], q3 = Wpsv[(f + 3) * 64 + g];
#pragma unroll
    for (int i = 0; i < 4; ++i) {
      float4 so = *(const float4*)(&xch[wv][i][0][f]);
      float4 u0 = *(const float4*)(&xch[wv][i][1][f]);
      float4 u1 = *(const float4*)(&xch[wv][i][2][f]);
      float4 u2 = *(const float4*)(&xch[wv][i][3][f]);
      s4[i]    += so.x * p0 + so.y * p1 + so.z * p2 + so.w * p3;
      v4[i][0] += u0.x * q0 + u0.y * q1 + u0.z * q2 + u0.w * q3;
      v4[i][1] += u1.x * q0 + u1.y * q1 + u1.z * q2 + u1.w * q3;
      v4[i][2] += u2.x * q0 + u2.y * q1 + u2.z * q2 + u2.w * q3;
    }
  }
  float wo = Wout[g];
#pragma unroll
  for (int i = 0; i < 4; ++i) {
    int n = n0 + i;
    float sf = s4[i] * INV8 + sks[i] * INVZ;
    float fx = v4[i][0] * INV8 + skv[i][0] * INVZ;
    float fy = v4[i][1] * INV8 + skv[i][1] * INVZ;
    float fz = v4[i][2] * INV8 + skv[i][2] * INVZ;
    float* orow = out + NN + (size_t)n * 256;
    orow[g] = sf;
    orow[64 + g * 3 + 0] = fx;
    orow[64 + g * 3 + 1] = fy;
    orow[64 + g * 3 + 2] = fz;
    float tsum = sf * wo;
#pragma unroll
    for (int off = 32; off > 0; off >>= 1) tsum += __shfl_down(tsum, off);
    if (g == 0) out[n] = tsum * INV8;
  }
}

extern "C" void kernel_launch(void* const* d_in, const int* in_sizes, int n_in,
                              void* d_out, int out_size, void* d_ws, size_t ws_size,
                              hipStream_t stream) {
  (void)in_sizes; (void)n_in; (void)out_size; (void)ws_size;
  const float* vecs = (const float*)d_in[0];
  const float* nf   = (const float*)d_in[1];
  const float* re   = (const float*)d_in[2];
  const float* Wsks = (const float*)d_in[3];
  const float* Wskv = (const float*)d_in[4];
  const float* Wups = (const float*)d_in[5];
  const float* Wupv = (const float*)d_in[6];
  const float* W1   = (const float*)d_in[7];
  const float* W2   = (const float*)d_in[8];
  const float* W3   = (const float*)d_in[9];
  const float* W4   = (const float*)d_in[10];
  const float* Wdns = (const float*)d_in[11];
  const float* Wdnv = (const float*)d_in[12];
  const float* Wsc  = (const float*)d_in[13];
  const float* Wpss = (const float*)d_in[14];
  const float* Wpsv = (const float*)d_in[15];
  const float* Wout = (const float*)d_in[16];
  const int* species = (const int*)d_in[17];
  const int* snd     = (const int*)d_in[18];
  const int* rcv     = (const int*)d_in[19];

  float* ws = (float*)d_ws;
  float* s_up  = ws;                        // N*64
  float* v_up  = ws + 2097152;              // N*192
  float* acc   = ws + 8388608;              // N*256
  float* wT    = ws + 16777216;             // 8704
  int* row_st  = (int*)(ws + 16785920);     // 32769 (+pad)
  int* cursor  = (int*)(ws + 16818692);     // 32768
  int* elist   = (int*)(ws + 16851460);     // 262144
  float* m_buf = ws + 17113604;             // EC*256

  float* W1T = wT;
  float* W2T = wT + 512;
  float* W3T = wT + 4608;

  hipMemsetAsync(cursor, 0, NN * sizeof(int), stream);
  hipMemsetAsync(acc, 0, (size_t)NN * 256 * sizeof(float), stream);
  k_wt<<<34, 256, 0, stream>>>(W1, W2, W3, wT);
  k_hist<<<EE / 256, 256, 0, stream>>>(rcv, cursor);
  k_scan<<<1, 1024, 0, stream>>>(cursor, row_st, cursor);
  k_fill<<<EE / 256, 256, 0, stream>>>(rcv, cursor, elist);
  k_up<<<2048, 256, 0, stream>>>(nf, Wups, Wupv, s_up, v_up);
  for (int c = 0; c < 4; ++c) {
    k_edge<<<EC / 128, 128, 0, stream>>>(vecs, re, W1T, W2T, W3T, W4,
                                         s_up, v_up, snd, elist,
                                         c * EC, m_buf);
    k_gather<<<NN / 4, 256, 0, stream>>>(m_buf, row_st, acc,
                                         c * EC, (c + 1) * EC);
  }
  k_post<<<2048, 256, 0, stream>>>(nf, acc, Wdns, Wdnv, Wsks, Wskv, Wsc,
                                   Wpss, Wpsv, Wout, species, (float*)d_out);
}

// Round 5
// 1340.655 us; speedup vs baseline: 3.0144x; 1.2003x over previous
//
#include <hip/hip_runtime.h>
#include <math.h>

// ---------------------------------------------------------------------------
// MACE layer, round 5.
//  - k_edge launches were grid-starved (512 blocks = 1 wave/SIMD -> 12%
//    occupancy, latency-bound at VALUBusy 14%). Messages now bf16 -> chunk
//    doubles to 131072 edges (1024 blocks, 8 waves/CU) in the same ~136 MB
//    proven workspace footprint; k_gather read traffic halves.
//  - edge geometry/sender loads hoisted above the MLP for latency overlap.
//
// Workspace layout (floats, ~136 MB):
//   s_up   [N*64]        @ 0
//   v_up   [N*192]       @ 2097152
//   acc    [N*256]       @ 8388608   (zeroed per call)
//   wT     [8704]        @ 16777216  (W1T 512 | W2T 4096 | W3T 4096)
//   row_st [32772 ints]  @ 16785920
//   cursor [32768 ints]  @ 16818692
//   elist  [262144 ints] @ 16851460
//   m_buf  [EC*256 bf16] @ 17113604  (67 MB as ushort)
// ---------------------------------------------------------------------------

#define NN 32768
#define EE 262144
#define EC 131072                        // edges per chunk (2 chunks)
#define INV8 0.125f                      // 1/sqrt(64)
#define INV_SQRT8 0.35355339059327373f   // 1/sqrt(8)
#define INVZ 0.039528470752104741f       // 1/sqrt(64*10)
#define EPS_C 0.25f
#define RS2 0.70710678118654752f         // 1/sqrt(2)

__device__ __forceinline__ unsigned bfpair(float lo, float hi) {
  unsigned ul = __float_as_uint(lo);
  unsigned uh = __float_as_uint(hi);
  ul = (ul + 0x7FFFu + ((ul >> 16) & 1u)) >> 16;
  uh = (uh + 0x7FFFu + ((uh >> 16) & 1u)) >> 16;
  return ul | (uh << 16);
}

// Transpose only the MLP weights needed for wave-uniform s_load rows.
__global__ __launch_bounds__(256) void k_wt(
    const float* __restrict__ W1, const float* __restrict__ W2,
    const float* __restrict__ W3, float* __restrict__ dst) {
  int i = blockIdx.x * 256 + threadIdx.x;  // 8704 total
  if (i < 512) {
    dst[i] = W1[(i & 7) * 64 + (i >> 3)];          // W1T[j][r]
  } else if (i < 4608) {
    int i2 = i - 512;
    dst[i] = W2[(i2 & 63) * 64 + (i2 >> 6)];       // W2T[j][k]
  } else {
    int i3 = i - 4608;
    dst[i] = W3[(i3 & 63) * 64 + (i3 >> 6)];       // W3T[j][k]
  }
}

__global__ __launch_bounds__(256) void k_hist(const int* __restrict__ rcv,
                                              int* __restrict__ cnt) {
  int e = blockIdx.x * 256 + threadIdx.x;
  atomicAdd(&cnt[rcv[e]], 1);
}

__global__ __launch_bounds__(1024) void k_scan(const int* __restrict__ cnt,
                                               int* __restrict__ row_start,
                                               int* __restrict__ cursor) {
  __shared__ int tot[1024];
  int t = threadIdx.x;
  int base = t * 32;
  int local[32];
  int s = 0;
#pragma unroll
  for (int i = 0; i < 32; ++i) { local[i] = s; s += cnt[base + i]; }
  tot[t] = s;
  __syncthreads();
  for (int off = 1; off < 1024; off <<= 1) {
    int v = (t >= off) ? tot[t - off] : 0;
    __syncthreads();
    tot[t] += v;
    __syncthreads();
  }
  int prefix = (t == 0) ? 0 : tot[t - 1];
#pragma unroll
  for (int i = 0; i < 32; ++i) {
    int v = prefix + local[i];
    row_start[base + i] = v;
    cursor[base + i] = v;
  }
  if (t == 1023) row_start[NN] = prefix + s;
}

__global__ __launch_bounds__(256) void k_fill(const int* __restrict__ rcv,
                                              int* __restrict__ cursor,
                                              int* __restrict__ elist) {
  int e = blockIdx.x * 256 + threadIdx.x;
  int pos = atomicAdd(&cursor[rcv[e]], 1);
  elist[pos] = e;
}

// linear_up: lane g = output channel; weights original layout -> coalesced;
// node data broadcast. 4 nodes per wave.
__global__ __launch_bounds__(256) void k_up(
    const float* __restrict__ nf,
    const float* __restrict__ Wups, const float* __restrict__ Wupv,
    float* __restrict__ s_up, float* __restrict__ v_up) {
  int g = threadIdx.x & 63;
  int n0 = (blockIdx.x * 4 + (threadIdx.x >> 6)) * 4;
  float su[4] = {0.f, 0.f, 0.f, 0.f};
  float vu[4][3] = {{0,0,0},{0,0,0},{0,0,0},{0,0,0}};
  for (int fq = 0; fq < 16; ++fq) {
    int f = fq * 4;
    float ws0 = Wups[(f + 0) * 64 + g], ws1 = Wups[(f + 1) * 64 + g];
    float ws2 = Wups[(f + 2) * 64 + g], ws3 = Wups[(f + 3) * 64 + g];
    float wv0 = Wupv[(f + 0) * 64 + g], wv1 = Wupv[(f + 1) * 64 + g];
    float wv2 = Wupv[(f + 2) * 64 + g], wv3 = Wupv[(f + 3) * 64 + g];
#pragma unroll
    for (int i = 0; i < 4; ++i) {
      const float* row = nf + (size_t)(n0 + i) * 256;
      float4 s4 = *(const float4*)(row + f);
      const float4* vr = (const float4*)(row + 64 + fq * 12);
      float4 va = vr[0], vb = vr[1], vc = vr[2];
      su[i]    += s4.x * ws0 + s4.y * ws1 + s4.z * ws2 + s4.w * ws3;
      vu[i][0] += va.x * wv0 + va.w * wv1 + vb.z * wv2 + vc.y * wv3;
      vu[i][1] += va.y * wv0 + vb.x * wv1 + vb.w * wv2 + vc.z * wv3;
      vu[i][2] += va.z * wv0 + vb.y * wv1 + vc.x * wv2 + vc.w * wv3;
    }
  }
#pragma unroll
  for (int i = 0; i < 4; ++i) {
    int n = n0 + i;
    s_up[n * 64 + g] = su[i] * INV8;
    v_up[(n * 3 + 0) * 64 + g] = vu[i][0] * INV8;
    v_up[(n * 3 + 1) * 64 + g] = vu[i][1] * INV8;
    v_up[(n * 3 + 2) * 64 + g] = vu[i][2] * INV8;
  }
}

__device__ __forceinline__ float silu_f(float x) {
  return x / (1.0f + __expf(-x));
}

// thread-per-edge in CSR order. h1 regs -> h2 LDS (64 f/thread, swizzled,
// conflict-free) -> h3 regs -> layer4+TP -> bf16 message store.
__global__ __launch_bounds__(128) void k_edge(
    const float* __restrict__ vecs, const float* __restrict__ re,
    const float* __restrict__ W1T, const float* __restrict__ W2T,
    const float* __restrict__ W3T, const float* __restrict__ W4,
    const float* __restrict__ s_up, const float* __restrict__ v_up,
    const int* __restrict__ snd, const int* __restrict__ elist,
    int e0, unsigned short* __restrict__ m_buf) {
  __shared__ float lh[128 * 64];  // 32 KB
  int t = threadIdx.x;
  int ip = blockIdx.x * 128 + t;       // chunk-local CSR position
  int e = elist[e0 + ip];
  float* hb = lh + t * 64;

  // hoist edge geometry + gather indices: issue loads before the MLP
  float ex = vecs[(size_t)e * 3 + 0];
  float ey = vecs[(size_t)e * 3 + 1];
  float ez = vecs[(size_t)e * 3 + 2];
  int se = snd[e];

  float r8[8];
  {
    const float4* rp = (const float4*)(re + (size_t)e * 8);
    float4 ra = rp[0], rb = rp[1];
    r8[0] = ra.x; r8[1] = ra.y; r8[2] = ra.z; r8[3] = ra.w;
    r8[4] = rb.x; r8[5] = rb.y; r8[6] = rb.z; r8[7] = rb.w;
  }

  // layer 1 -> h1 registers
  float h1[64];
#pragma unroll
  for (int j = 0; j < 64; ++j) {
    const float* w = W1T + j * 8;      // uniform -> s_load
    float a = 0.f;
#pragma unroll
    for (int r = 0; r < 8; ++r) a += r8[r] * w[r];
    h1[j] = silu_f(a * INV_SQRT8);
  }

  // layer 2: h1 regs -> h2 LDS (swizzled (j+t)&63: 2 lanes/bank = free)
#pragma unroll 1
  for (int j = 0; j < 64; ++j) {
    const float* w = W2T + j * 64;     // uniform -> s_load rows
    float a = 0.f;
#pragma unroll
    for (int k = 0; k < 64; ++k) a += h1[k] * w[k];
    hb[(j + t) & 63] = silu_f(a * INV8);
  }

  // layer 3: h2 LDS -> h3 regs
  float h3[64];
#pragma unroll
  for (int g8 = 0; g8 < 8; ++g8) {
    float a8[8] = {0, 0, 0, 0, 0, 0, 0, 0};
#pragma unroll 1
    for (int k16 = 0; k16 < 4; ++k16) {
      float hc[16];
#pragma unroll
      for (int k = 0; k < 16; ++k) hc[k] = hb[(k16 * 16 + k + t) & 63];
#pragma unroll
      for (int jj = 0; jj < 8; ++jj) {
        const float* w = W3T + (g8 * 8 + jj) * 64 + k16 * 16;  // uniform
        float a = 0.f;
#pragma unroll
        for (int k = 0; k < 16; ++k) a += hc[k] * w[k];
        a8[jj] += a;
      }
    }
#pragma unroll
    for (int jj = 0; jj < 8; ++jj)
      h3[g8 * 8 + jj] = silu_f(a8[jj] * INV8);
  }

  float rn = 1.0f / (sqrtf(ex * ex + ey * ey + ez * ez) + 1e-9f);
  float Yx = ex * rn, Yy = ey * rn, Yz = ez * rn;
  const float* srow = s_up + (size_t)se * 64;
  const float* vrow = v_up + (size_t)se * 192;
  unsigned short* mrow = m_buf + (size_t)ip * 256;
  const float C = EPS_C * INV8;  // fold layer4 1/sqrt(H) + EPS into store

  // layer 4 (h3 @ W4) fused with TP + contiguous bf16 message store
#pragma unroll 1
  for (int fb = 0; fb < 8; ++fb) {
    float w[5][8];
#pragma unroll
    for (int p = 0; p < 5; ++p)
#pragma unroll
      for (int j = 0; j < 8; ++j) w[p][j] = 0.0f;
#pragma unroll
    for (int k = 0; k < 64; ++k) {
      const float* wr = W4 + k * 320 + fb * 8;  // uniform -> s_load_dwordx8
      float hk = h3[k];
#pragma unroll
      for (int p = 0; p < 5; ++p)
#pragma unroll
        for (int j = 0; j < 8; ++j) w[p][j] += hk * wr[p * 64 + j];
    }
    float4 s0 = *(const float4*)(srow + fb * 8);
    float4 s1 = *(const float4*)(srow + fb * 8 + 4);
    float4 x0 = *(const float4*)(vrow + fb * 8);
    float4 x1 = *(const float4*)(vrow + fb * 8 + 4);
    float4 y0 = *(const float4*)(vrow + 64 + fb * 8);
    float4 y1 = *(const float4*)(vrow + 64 + fb * 8 + 4);
    float4 z0 = *(const float4*)(vrow + 128 + fb * 8);
    float4 z1 = *(const float4*)(vrow + 128 + fb * 8 + 4);
    float ssv[8] = {s0.x, s0.y, s0.z, s0.w, s1.x, s1.y, s1.z, s1.w};
    float vxv[8] = {x0.x, x0.y, x0.z, x0.w, x1.x, x1.y, x1.z, x1.w};
    float vyv[8] = {y0.x, y0.y, y0.z, y0.w, y1.x, y1.y, y1.z, y1.w};
    float vzv[8] = {z0.x, z0.y, z0.z, z0.w, z1.x, z1.y, z1.z, z1.w};
    float ms[8], mx[8], my[8], mz[8];
#pragma unroll
    for (int j = 0; j < 8; ++j) {
      float vvx = vxv[j], vvy = vyv[j], vvz = vzv[j];
      float dt = vvx * Yx + vvy * Yy + vvz * Yz;
      float cx = vvy * Yz - vvz * Yy;
      float cy = vvz * Yx - vvx * Yz;
      float cz = vvx * Yy - vvy * Yx;
      ms[j] = C * (w[0][j] * ssv[j] + w[3][j] * dt);
      mx[j] = C * (w[1][j] * Yx + w[2][j] * vvx + w[4][j] * (cx * RS2));
      my[j] = C * (w[1][j] * Yy + w[2][j] * vvy + w[4][j] * (cy * RS2));
      mz[j] = C * (w[1][j] * Yz + w[2][j] * vvz + w[4][j] * (cz * RS2));
    }
    uint4 pk;
    pk.x = bfpair(ms[0], ms[1]); pk.y = bfpair(ms[2], ms[3]);
    pk.z = bfpair(ms[4], ms[5]); pk.w = bfpair(ms[6], ms[7]);
    *(uint4*)(mrow + fb * 8) = pk;
    pk.x = bfpair(mx[0], mx[1]); pk.y = bfpair(mx[2], mx[3]);
    pk.z = bfpair(mx[4], mx[5]); pk.w = bfpair(mx[6], mx[7]);
    *(uint4*)(mrow + 64 + fb * 8) = pk;
    pk.x = bfpair(my[0], my[1]); pk.y = bfpair(my[2], my[3]);
    pk.z = bfpair(my[4], my[5]); pk.w = bfpair(my[6], my[7]);
    *(uint4*)(mrow + 128 + fb * 8) = pk;
    pk.x = bfpair(mz[0], mz[1]); pk.y = bfpair(mz[2], mz[3]);
    pk.z = bfpair(mz[4], mz[5]); pk.w = bfpair(mz[6], mz[7]);
    *(uint4*)(mrow + 192 + fb * 8) = pk;
  }
}

// one wave per node; contiguous clipped CSR range [lo,hi) of this chunk.
// lane g accumulates elements [4g, 4g+4) (uint2 = 4 bf16 per message row).
__global__ __launch_bounds__(256) void k_gather(
    const unsigned short* __restrict__ m_buf,
    const int* __restrict__ row_start,
    float* __restrict__ acc, int e0, int e1) {
  int g = threadIdx.x & 63;
  int wv = threadIdx.x >> 6;
  int n = blockIdx.x * 4 + wv;
  int beg = row_start[n], end = row_start[n + 1];
  int lo = beg > e0 ? beg : e0;
  int hi = end < e1 ? end : e1;
  if (lo >= hi) return;
  float4 a = make_float4(0.f, 0.f, 0.f, 0.f);
  for (int i = lo; i < hi; ++i) {
    uint2 m = *(const uint2*)(m_buf + (size_t)(i - e0) * 256 + g * 4);
    a.x += __uint_as_float(m.x << 16);
    a.y += __uint_as_float(m.x & 0xFFFF0000u);
    a.z += __uint_as_float(m.y << 16);
    a.w += __uint_as_float(m.y & 0xFFFF0000u);
  }
  float* dst = acc + (size_t)n * 256 + g * 4;
  float4 p = *(const float4*)dst;  // serialized chunks: RMW is safe
  *(float4*)dst = make_float4(a.x + p.x, a.y + p.y, a.z + p.z, a.w + p.w);
}

__global__ __launch_bounds__(256) void k_post(
    const float* __restrict__ nf, const float* __restrict__ acc,
    const float* __restrict__ Wdns, const float* __restrict__ Wdnv,
    const float* __restrict__ Wsks, const float* __restrict__ Wskv,
    const float* __restrict__ Wsc,
    const float* __restrict__ Wpss, const float* __restrict__ Wpsv,
    const float* __restrict__ Wout, const int* __restrict__ species,
    float* __restrict__ out) {
  __shared__ __align__(16) float xch[4][4][4][68];
  int g = threadIdx.x & 63;
  int wv = threadIdx.x >> 6;
  int n0 = (blockIdx.x * 4 + wv) * 4;
  int spec[4];
#pragma unroll
  for (int i = 0; i < 4; ++i) spec[i] = species[n0 + i];
  float s3[4] = {0, 0, 0, 0};
  float v3[4][3] = {{0,0,0},{0,0,0},{0,0,0},{0,0,0}};
  float sks[4] = {0, 0, 0, 0};
  float skv[4][3] = {{0,0,0},{0,0,0},{0,0,0},{0,0,0}};
  for (int fq = 0; fq < 16; ++fq) {
    int f = fq * 4;
    float d0 = Wdns[(f + 0) * 64 + g], d1 = Wdns[(f + 1) * 64 + g];
    float d2 = Wdns[(f + 2) * 64 + g], d3 = Wdns[(f + 3) * 64 + g];
    float e0 = Wdnv[(f + 0) * 64 + g], e1 = Wdnv[(f + 1) * 64 + g];
    float e2 = Wdnv[(f + 2) * 64 + g], e3 = Wdnv[(f + 3) * 64 + g];
#pragma unroll
    for (int i = 0; i < 4; ++i) {
      int n = n0 + i;
      const float* arow = acc + (size_t)n * 256;
      float4 sa = *(const float4*)(arow + f);
      float4 vx = *(const float4*)(arow + 64 + f);
      float4 vy = *(const float4*)(arow + 128 + f);
      float4 vz = *(const float4*)(arow + 192 + f);
      s3[i]    += sa.x * d0 + sa.y * d1 + sa.z * d2 + sa.w * d3;
      v3[i][0] += vx.x * e0 + vx.y * e1 + vx.z * e2 + vx.w * e3;
      v3[i][1] += vy.x * e0 + vy.y * e1 + vy.z * e2 + vy.w * e3;
      v3[i][2] += vz.x * e0 + vz.y * e1 + vz.z * e2 + vz.w * e3;
      const float* ksb = Wsks + spec[i] * 4096 + f * 64 + g;  // coalesced
      const float* kvb = Wskv + spec[i] * 4096 + f * 64 + g;
      float k0 = ksb[0], k1 = ksb[64], k2 = ksb[128], k3 = ksb[192];
      float q0 = kvb[0], q1 = kvb[64], q2 = kvb[128], q3 = kvb[192];
      const float* row = nf + (size_t)n * 256;
      float4 s04 = *(const float4*)(row + f);
      const float4* vr = (const float4*)(row + 64 + fq * 12);
      float4 va = vr[0], vb = vr[1], vc = vr[2];
      sks[i]    += s04.x * k0 + s04.y * k1 + s04.z * k2 + s04.w * k3;
      skv[i][0] += va.x * q0 + va.w * q1 + vb.z * q2 + vc.y * q3;
      skv[i][1] += va.y * q0 + vb.x * q1 + vb.w * q2 + vc.z * q3;
      skv[i][2] += va.z * q0 + vb.y * q1 + vc.x * q2 + vc.w * q3;
    }
  }
#pragma unroll
  for (int i = 0; i < 4; ++i) {
    float s = s3[i] * INV8;
    float vx = v3[i][0] * INV8, vy = v3[i][1] * INV8, vz = v3[i][2] * INV8;
    float vn2 = vx * vx + vy * vy + vz * vz;
    const float* wz = Wsc + spec[i] * 576 + g;
    float w0 = wz[0], w1 = wz[64], w2 = wz[128], w3 = wz[192], w4 = wz[256];
    float w5 = wz[320], w6 = wz[384], w7 = wz[448], w8 = wz[512];
    float s_o = w0 * s + w1 * s * s + w2 * vn2 + w3 * s * s * s + w4 * s * vn2;
    float vcm = w5 + w6 * s + w7 * s * s + w8 * vn2;
    xch[wv][i][0][g] = s_o;
    xch[wv][i][1][g] = vcm * vx;
    xch[wv][i][2][g] = vcm * vy;
    xch[wv][i][3][g] = vcm * vz;
  }
  __syncthreads();
  float s4[4] = {0, 0, 0, 0};
  float v4[4][3] = {{0,0,0},{0,0,0},{0,0,0},{0,0,0}};
  for (int fq = 0; fq < 16; ++fq) {
    int f = fq * 4;
    float p0 = Wpss[(f + 0) * 64 + g], p1 = Wpss[(f + 1) * 64 + g];
    float p2 = Wpss[(f + 2) * 64 + g], p3 = Wpss[(f + 3) * 64 + g];
    float q0 = Wpsv[(f + 0) * 64 + g], q1 = Wpsv[(f + 1) * 64 + g];
    float q2 = Wpsv[(f + 2) * 64 + g], q3 = Wpsv[(f + 3) * 64 + g];
#pragma unroll
    for (int i = 0; i < 4; ++i) {
      float4 so = *(const float4*)(&xch[wv][i][0][f]);
      float4 u0 = *(const float4*)(&xch[wv][i][1][f]);
      float4 u1 = *(const float4*)(&xch[wv][i][2][f]);
      float4 u2 = *(const float4*)(&xch[wv][i][3][f]);
      s4[i]    += so.x * p0 + so.y * p1 + so.z * p2 + so.w * p3;
      v4[i][0] += u0.x * q0 + u0.y * q1 + u0.z * q2 + u0.w * q3;
      v4[i][1] += u1.x * q0 + u1.y * q1 + u1.z * q2 + u1.w * q3;
      v4[i][2] += u2.x * q0 + u2.y * q1 + u2.z * q2 + u2.w * q3;
    }
  }
  float wo = Wout[g];
#pragma unroll
  for (int i = 0; i < 4; ++i) {
    int n = n0 + i;
    float sf = s4[i] * INV8 + sks[i] * INVZ;
    float fx = v4[i][0] * INV8 + skv[i][0] * INVZ;
    float fy = v4[i][1] * INV8 + skv[i][1] * INVZ;
    float fz = v4[i][2] * INV8 + skv[i][2] * INVZ;
    float* orow = out + NN + (size_t)n * 256;
    orow[g] = sf;
    orow[64 + g * 3 + 0] = fx;
    orow[64 + g * 3 + 1] = fy;
    orow[64 + g * 3 + 2] = fz;
    float tsum = sf * wo;
#pragma unroll
    for (int off = 32; off > 0; off >>= 1) tsum += __shfl_down(tsum, off);
    if (g == 0) out[n] = tsum * INV8;
  }
}

extern "C" void kernel_launch(void* const* d_in, const int* in_sizes, int n_in,
                              void* d_out, int out_size, void* d_ws, size_t ws_size,
                              hipStream_t stream) {
  (void)in_sizes; (void)n_in; (void)out_size; (void)ws_size;
  const float* vecs = (const float*)d_in[0];
  const float* nf   = (const float*)d_in[1];
  const float* re   = (const float*)d_in[2];
  const float* Wsks = (const float*)d_in[3];
  const float* Wskv = (const float*)d_in[4];
  const float* Wups = (const float*)d_in[5];
  const float* Wupv = (const float*)d_in[6];
  const float* W1   = (const float*)d_in[7];
  const float* W2   = (const float*)d_in[8];
  const float* W3   = (const float*)d_in[9];
  const float* W4   = (const float*)d_in[10];
  const float* Wdns = (const float*)d_in[11];
  const float* Wdnv = (const float*)d_in[12];
  const float* Wsc  = (const float*)d_in[13];
  const float* Wpss = (const float*)d_in[14];
  const float* Wpsv = (const float*)d_in[15];
  const float* Wout = (const float*)d_in[16];
  const int* species = (const int*)d_in[17];
  const int* snd     = (const int*)d_in[18];
  const int* rcv     = (const int*)d_in[19];

  float* ws = (float*)d_ws;
  float* s_up  = ws;                        // N*64
  float* v_up  = ws + 2097152;              // N*192
  float* acc   = ws + 8388608;              // N*256
  float* wT    = ws + 16777216;             // 8704
  int* row_st  = (int*)(ws + 16785920);     // 32769 (+pad)
  int* cursor  = (int*)(ws + 16818692);     // 32768
  int* elist   = (int*)(ws + 16851460);     // 262144
  unsigned short* m_buf = (unsigned short*)(ws + 17113604);  // EC*256 bf16

  float* W1T = wT;
  float* W2T = wT + 512;
  float* W3T = wT + 4608;

  hipMemsetAsync(cursor, 0, NN * sizeof(int), stream);
  hipMemsetAsync(acc, 0, (size_t)NN * 256 * sizeof(float), stream);
  k_wt<<<34, 256, 0, stream>>>(W1, W2, W3, wT);
  k_hist<<<EE / 256, 256, 0, stream>>>(rcv, cursor);
  k_scan<<<1, 1024, 0, stream>>>(cursor, row_st, cursor);
  k_fill<<<EE / 256, 256, 0, stream>>>(rcv, cursor, elist);
  k_up<<<2048, 256, 0, stream>>>(nf, Wups, Wupv, s_up, v_up);
  for (int c = 0; c < 2; ++c) {
    k_edge<<<EC / 128, 128, 0, stream>>>(vecs, re, W1T, W2T, W3T, W4,
                                         s_up, v_up, snd, elist,
                                         c * EC, m_buf);
    k_gather<<<NN / 4, 256, 0, stream>>>(m_buf, row_st, acc,
                                         c * EC, (c + 1) * EC);
  }
  k_post<<<2048, 256, 0, stream>>>(nf, acc, Wdns, Wdnv, Wsks, Wskv, Wsc,
                                   Wpss, Wpsv, Wout, species, (float*)d_out);
}

// Round 6
// 1123.143 us; speedup vs baseline: 3.5981x; 1.1937x over previous
//
#include <hip/hip_runtime.h>
#include <math.h>

// ---------------------------------------------------------------------------
// MACE layer, round 6.
//  - Layer-4 weights reordered (W4R[fb][k][40] contiguous) -> streaming wide
//    s_loads instead of 2560 scattered 32B s_loads per wave (the ~90% stall).
//  - Layer 2 restructured to 8 independent accumulator chains (jb-blocked),
//    consuming W2 in original layout (contiguous dwordx8 per (k,jb)).
//  - Rest identical to round 5 (CSR ordering, bf16 messages, 2 chunks).
//
// Workspace layout (floats, ~136 MB):
//   s_up   [N*64]        @ 0
//   v_up   [N*192]       @ 2097152
//   acc    [N*256]       @ 8388608   (zeroed per call)
//   wT     [25088]       @ 16777216  (W1T 512 | W3T 4096 | W4R 20480)
//   row_st [32772 ints]  @ 16802304
//   cursor [32768 ints]  @ 16835076
//   elist  [262144 ints] @ 16867844
//   m_buf  [EC*256 bf16] @ 17129988  (67 MB as ushort)
// ---------------------------------------------------------------------------

#define NN 32768
#define EE 262144
#define EC 131072                        // edges per chunk (2 chunks)
#define INV8 0.125f                      // 1/sqrt(64)
#define INV_SQRT8 0.35355339059327373f   // 1/sqrt(8)
#define INVZ 0.039528470752104741f       // 1/sqrt(64*10)
#define EPS_C 0.25f
#define RS2 0.70710678118654752f         // 1/sqrt(2)

__device__ __forceinline__ unsigned bfpair(float lo, float hi) {
  unsigned ul = __float_as_uint(lo);
  unsigned uh = __float_as_uint(hi);
  ul = (ul + 0x7FFFu + ((ul >> 16) & 1u)) >> 16;
  uh = (uh + 0x7FFFu + ((uh >> 16) & 1u)) >> 16;
  return ul | (uh << 16);
}

// W1T[j][r] (512) | W3T[j][k] (4096) | W4R[fb][k][p*8+j] (20480)
__global__ __launch_bounds__(256) void k_wt(
    const float* __restrict__ W1, const float* __restrict__ W3,
    const float* __restrict__ W4, float* __restrict__ dst) {
  int i = blockIdx.x * 256 + threadIdx.x;  // 25088 total
  if (i < 512) {
    dst[i] = W1[(i & 7) * 64 + (i >> 3)];           // W1T[j][r]
  } else if (i < 4608) {
    int i2 = i - 512;
    dst[i] = W3[(i2 & 63) * 64 + (i2 >> 6)];        // W3T[j][k]
  } else {
    int i4 = i - 4608;                               // fb*2560 + k*40 + p*8 + j
    int fb = i4 / 2560;
    int r = i4 - fb * 2560;
    int k = r / 40;
    int pj = r - k * 40;                             // p*8+j
    int p = pj >> 3, j = pj & 7;
    dst[i] = W4[k * 320 + p * 64 + fb * 8 + j];
  }
}

__global__ __launch_bounds__(256) void k_hist(const int* __restrict__ rcv,
                                              int* __restrict__ cnt) {
  int e = blockIdx.x * 256 + threadIdx.x;
  atomicAdd(&cnt[rcv[e]], 1);
}

__global__ __launch_bounds__(1024) void k_scan(const int* __restrict__ cnt,
                                               int* __restrict__ row_start,
                                               int* __restrict__ cursor) {
  __shared__ int tot[1024];
  int t = threadIdx.x;
  int base = t * 32;
  int local[32];
  int s = 0;
#pragma unroll
  for (int i = 0; i < 32; ++i) { local[i] = s; s += cnt[base + i]; }
  tot[t] = s;
  __syncthreads();
  for (int off = 1; off < 1024; off <<= 1) {
    int v = (t >= off) ? tot[t - off] : 0;
    __syncthreads();
    tot[t] += v;
    __syncthreads();
  }
  int prefix = (t == 0) ? 0 : tot[t - 1];
#pragma unroll
  for (int i = 0; i < 32; ++i) {
    int v = prefix + local[i];
    row_start[base + i] = v;
    cursor[base + i] = v;
  }
  if (t == 1023) row_start[NN] = prefix + s;
}

__global__ __launch_bounds__(256) void k_fill(const int* __restrict__ rcv,
                                              int* __restrict__ cursor,
                                              int* __restrict__ elist) {
  int e = blockIdx.x * 256 + threadIdx.x;
  int pos = atomicAdd(&cursor[rcv[e]], 1);
  elist[pos] = e;
}

// linear_up: lane g = output channel; weights original layout -> coalesced;
// node data broadcast. 4 nodes per wave.
__global__ __launch_bounds__(256) void k_up(
    const float* __restrict__ nf,
    const float* __restrict__ Wups, const float* __restrict__ Wupv,
    float* __restrict__ s_up, float* __restrict__ v_up) {
  int g = threadIdx.x & 63;
  int n0 = (blockIdx.x * 4 + (threadIdx.x >> 6)) * 4;
  float su[4] = {0.f, 0.f, 0.f, 0.f};
  float vu[4][3] = {{0,0,0},{0,0,0},{0,0,0},{0,0,0}};
  for (int fq = 0; fq < 16; ++fq) {
    int f = fq * 4;
    float ws0 = Wups[(f + 0) * 64 + g], ws1 = Wups[(f + 1) * 64 + g];
    float ws2 = Wups[(f + 2) * 64 + g], ws3 = Wups[(f + 3) * 64 + g];
    float wv0 = Wupv[(f + 0) * 64 + g], wv1 = Wupv[(f + 1) * 64 + g];
    float wv2 = Wupv[(f + 2) * 64 + g], wv3 = Wupv[(f + 3) * 64 + g];
#pragma unroll
    for (int i = 0; i < 4; ++i) {
      const float* row = nf + (size_t)(n0 + i) * 256;
      float4 s4 = *(const float4*)(row + f);
      const float4* vr = (const float4*)(row + 64 + fq * 12);
      float4 va = vr[0], vb = vr[1], vc = vr[2];
      su[i]    += s4.x * ws0 + s4.y * ws1 + s4.z * ws2 + s4.w * ws3;
      vu[i][0] += va.x * wv0 + va.w * wv1 + vb.z * wv2 + vc.y * wv3;
      vu[i][1] += va.y * wv0 + vb.x * wv1 + vb.w * wv2 + vc.z * wv3;
      vu[i][2] += va.z * wv0 + vb.y * wv1 + vc.x * wv2 + vc.w * wv3;
    }
  }
#pragma unroll
  for (int i = 0; i < 4; ++i) {
    int n = n0 + i;
    s_up[n * 64 + g] = su[i] * INV8;
    v_up[(n * 3 + 0) * 64 + g] = vu[i][0] * INV8;
    v_up[(n * 3 + 1) * 64 + g] = vu[i][1] * INV8;
    v_up[(n * 3 + 2) * 64 + g] = vu[i][2] * INV8;
  }
}

__device__ __forceinline__ float silu_f(float x) {
  return x / (1.0f + __expf(-x));
}

// thread-per-edge in CSR order. h1 regs -> h2 LDS (swizzled) -> h3 regs ->
// layer4+TP -> bf16 message store. All layers use 8-wide accumulator blocks.
__global__ __launch_bounds__(128) void k_edge(
    const float* __restrict__ vecs, const float* __restrict__ re,
    const float* __restrict__ W1T, const float* __restrict__ W2,
    const float* __restrict__ W3T, const float* __restrict__ W4R,
    const float* __restrict__ s_up, const float* __restrict__ v_up,
    const int* __restrict__ snd, const int* __restrict__ elist,
    int e0, unsigned short* __restrict__ m_buf) {
  __shared__ float lh[128 * 64];  // 32 KB
  int t = threadIdx.x;
  int ip = blockIdx.x * 128 + t;       // chunk-local CSR position
  int e = elist[e0 + ip];
  float* hb = lh + t * 64;

  // hoist edge geometry + gather indices: issue loads before the MLP
  float ex = vecs[(size_t)e * 3 + 0];
  float ey = vecs[(size_t)e * 3 + 1];
  float ez = vecs[(size_t)e * 3 + 2];
  int se = snd[e];

  float r8[8];
  {
    const float4* rp = (const float4*)(re + (size_t)e * 8);
    float4 ra = rp[0], rb = rp[1];
    r8[0] = ra.x; r8[1] = ra.y; r8[2] = ra.z; r8[3] = ra.w;
    r8[4] = rb.x; r8[5] = rb.y; r8[6] = rb.z; r8[7] = rb.w;
  }

  // layer 1 -> h1 registers (8-deep chains, tiny)
  float h1[64];
#pragma unroll
  for (int j = 0; j < 64; ++j) {
    const float* w = W1T + j * 8;      // uniform -> s_load
    float a = 0.f;
#pragma unroll
    for (int r = 0; r < 8; ++r) a += r8[r] * w[r];
    h1[j] = silu_f(a * INV_SQRT8);
  }

  // layer 2: h1 regs -> h2 LDS. jb-blocked: 8 independent chains; W2 original
  // layout -> one uniform dwordx8 per (k,jb).
#pragma unroll 1
  for (int jb = 0; jb < 8; ++jb) {
    float acc[8] = {0, 0, 0, 0, 0, 0, 0, 0};
#pragma unroll
    for (int k = 0; k < 64; ++k) {
      const float* wr = W2 + k * 64 + jb * 8;  // uniform -> s_load_dwordx8
      float hk = h1[k];
#pragma unroll
      for (int jj = 0; jj < 8; ++jj) acc[jj] += hk * wr[jj];
    }
#pragma unroll
    for (int jj = 0; jj < 8; ++jj)
      hb[(jb * 8 + jj + t) & 63] = silu_f(acc[jj] * INV8);
  }

  // layer 3: h2 LDS -> h3 regs (8 chains, 16-value LDS cache)
  float h3[64];
#pragma unroll
  for (int g8 = 0; g8 < 8; ++g8) {
    float a8[8] = {0, 0, 0, 0, 0, 0, 0, 0};
#pragma unroll 1
    for (int k16 = 0; k16 < 4; ++k16) {
      float hc[16];
#pragma unroll
      for (int k = 0; k < 16; ++k) hc[k] = hb[(k16 * 16 + k + t) & 63];
#pragma unroll
      for (int jj = 0; jj < 8; ++jj) {
        const float* w = W3T + (g8 * 8 + jj) * 64 + k16 * 16;  // uniform
        float a = 0.f;
#pragma unroll
        for (int k = 0; k < 16; ++k) a += hc[k] * w[k];
        a8[jj] += a;
      }
    }
#pragma unroll
    for (int jj = 0; jj < 8; ++jj)
      h3[g8 * 8 + jj] = silu_f(a8[jj] * INV8);
  }

  float rn = 1.0f / (sqrtf(ex * ex + ey * ey + ez * ez) + 1e-9f);
  float Yx = ex * rn, Yy = ey * rn, Yz = ez * rn;
  const float* srow = s_up + (size_t)se * 64;
  const float* vrow = v_up + (size_t)se * 192;
  unsigned short* mrow = m_buf + (size_t)ip * 256;
  const float C = EPS_C * INV8;  // fold layer4 1/sqrt(H) + EPS into store

  // layer 4: W4R[fb] is a contiguous 2560-float run, consumed sequentially.
#pragma unroll 1
  for (int fb = 0; fb < 8; ++fb) {
    const float* base = W4R + fb * 2560;
    float w[5][8];
#pragma unroll
    for (int p = 0; p < 5; ++p)
#pragma unroll
      for (int j = 0; j < 8; ++j) w[p][j] = 0.0f;
#pragma unroll
    for (int k = 0; k < 64; ++k) {
      const float* wr = base + k * 40;  // uniform, contiguous -> wide s_load
      float hk = h3[k];
#pragma unroll
      for (int p = 0; p < 5; ++p)
#pragma unroll
        for (int j = 0; j < 8; ++j) w[p][j] += hk * wr[p * 8 + j];
    }
    float4 s0 = *(const float4*)(srow + fb * 8);
    float4 s1 = *(const float4*)(srow + fb * 8 + 4);
    float4 x0 = *(const float4*)(vrow + fb * 8);
    float4 x1 = *(const float4*)(vrow + fb * 8 + 4);
    float4 y0 = *(const float4*)(vrow + 64 + fb * 8);
    float4 y1 = *(const float4*)(vrow + 64 + fb * 8 + 4);
    float4 z0 = *(const float4*)(vrow + 128 + fb * 8);
    float4 z1 = *(const float4*)(vrow + 128 + fb * 8 + 4);
    float ssv[8] = {s0.x, s0.y, s0.z, s0.w, s1.x, s1.y, s1.z, s1.w};
    float vxv[8] = {x0.x, x0.y, x0.z, x0.w, x1.x, x1.y, x1.z, x1.w};
    float vyv[8] = {y0.x, y0.y, y0.z, y0.w, y1.x, y1.y, y1.z, y1.w};
    float vzv[8] = {z0.x, z0.y, z0.z, z0.w, z1.x, z1.y, z1.z, z1.w};
    float ms[8], mx[8], my[8], mz[8];
#pragma unroll
    for (int j = 0; j < 8; ++j) {
      float vvx = vxv[j], vvy = vyv[j], vvz = vzv[j];
      float dt = vvx * Yx + vvy * Yy + vvz * Yz;
      float cx = vvy * Yz - vvz * Yy;
      float cy = vvz * Yx - vvx * Yz;
      float cz = vvx * Yy - vvy * Yx;
      ms[j] = C * (w[0][j] * ssv[j] + w[3][j] * dt);
      mx[j] = C * (w[1][j] * Yx + w[2][j] * vvx + w[4][j] * (cx * RS2));
      my[j] = C * (w[1][j] * Yy + w[2][j] * vvy + w[4][j] * (cy * RS2));
      mz[j] = C * (w[1][j] * Yz + w[2][j] * vvz + w[4][j] * (cz * RS2));
    }
    uint4 pk;
    pk.x = bfpair(ms[0], ms[1]); pk.y = bfpair(ms[2], ms[3]);
    pk.z = bfpair(ms[4], ms[5]); pk.w = bfpair(ms[6], ms[7]);
    *(uint4*)(mrow + fb * 8) = pk;
    pk.x = bfpair(mx[0], mx[1]); pk.y = bfpair(mx[2], mx[3]);
    pk.z = bfpair(mx[4], mx[5]); pk.w = bfpair(mx[6], mx[7]);
    *(uint4*)(mrow + 64 + fb * 8) = pk;
    pk.x = bfpair(my[0], my[1]); pk.y = bfpair(my[2], my[3]);
    pk.z = bfpair(my[4], my[5]); pk.w = bfpair(my[6], my[7]);
    *(uint4*)(mrow + 128 + fb * 8) = pk;
    pk.x = bfpair(mz[0], mz[1]); pk.y = bfpair(mz[2], mz[3]);
    pk.z = bfpair(mz[4], mz[5]); pk.w = bfpair(mz[6], mz[7]);
    *(uint4*)(mrow + 192 + fb * 8) = pk;
  }
}

// one wave per node; contiguous clipped CSR range [lo,hi) of this chunk.
__global__ __launch_bounds__(256) void k_gather(
    const unsigned short* __restrict__ m_buf,
    const int* __restrict__ row_start,
    float* __restrict__ acc, int e0, int e1) {
  int g = threadIdx.x & 63;
  int wv = threadIdx.x >> 6;
  int n = blockIdx.x * 4 + wv;
  int beg = row_start[n], end = row_start[n + 1];
  int lo = beg > e0 ? beg : e0;
  int hi = end < e1 ? end : e1;
  if (lo >= hi) return;
  float4 a = make_float4(0.f, 0.f, 0.f, 0.f);
  for (int i = lo; i < hi; ++i) {
    uint2 m = *(const uint2*)(m_buf + (size_t)(i - e0) * 256 + g * 4);
    a.x += __uint_as_float(m.x << 16);
    a.y += __uint_as_float(m.x & 0xFFFF0000u);
    a.z += __uint_as_float(m.y << 16);
    a.w += __uint_as_float(m.y & 0xFFFF0000u);
  }
  float* dst = acc + (size_t)n * 256 + g * 4;
  float4 p = *(const float4*)dst;  // serialized chunks: RMW is safe
  *(float4*)dst = make_float4(a.x + p.x, a.y + p.y, a.z + p.z, a.w + p.w);
}

__global__ __launch_bounds__(256) void k_post(
    const float* __restrict__ nf, const float* __restrict__ acc,
    const float* __restrict__ Wdns, const float* __restrict__ Wdnv,
    const float* __restrict__ Wsks, const float* __restrict__ Wskv,
    const float* __restrict__ Wsc,
    const float* __restrict__ Wpss, const float* __restrict__ Wpsv,
    const float* __restrict__ Wout, const int* __restrict__ species,
    float* __restrict__ out) {
  __shared__ __align__(16) float xch[4][4][4][68];
  int g = threadIdx.x & 63;
  int wv = threadIdx.x >> 6;
  int n0 = (blockIdx.x * 4 + wv) * 4;
  int spec[4];
#pragma unroll
  for (int i = 0; i < 4; ++i) spec[i] = species[n0 + i];
  float s3[4] = {0, 0, 0, 0};
  float v3[4][3] = {{0,0,0},{0,0,0},{0,0,0},{0,0,0}};
  float sks[4] = {0, 0, 0, 0};
  float skv[4][3] = {{0,0,0},{0,0,0},{0,0,0},{0,0,0}};
  for (int fq = 0; fq < 16; ++fq) {
    int f = fq * 4;
    float d0 = Wdns[(f + 0) * 64 + g], d1 = Wdns[(f + 1) * 64 + g];
    float d2 = Wdns[(f + 2) * 64 + g], d3 = Wdns[(f + 3) * 64 + g];
    float e0 = Wdnv[(f + 0) * 64 + g], e1 = Wdnv[(f + 1) * 64 + g];
    float e2 = Wdnv[(f + 2) * 64 + g], e3 = Wdnv[(f + 3) * 64 + g];
#pragma unroll
    for (int i = 0; i < 4; ++i) {
      int n = n0 + i;
      const float* arow = acc + (size_t)n * 256;
      float4 sa = *(const float4*)(arow + f);
      float4 vx = *(const float4*)(arow + 64 + f);
      float4 vy = *(const float4*)(arow + 128 + f);
      float4 vz = *(const float4*)(arow + 192 + f);
      s3[i]    += sa.x * d0 + sa.y * d1 + sa.z * d2 + sa.w * d3;
      v3[i][0] += vx.x * e0 + vx.y * e1 + vx.z * e2 + vx.w * e3;
      v3[i][1] += vy.x * e0 + vy.y * e1 + vy.z * e2 + vy.w * e3;
      v3[i][2] += vz.x * e0 + vz.y * e1 + vz.z * e2 + vz.w * e3;
      const float* ksb = Wsks + spec[i] * 4096 + f * 64 + g;  // coalesced
      const float* kvb = Wskv + spec[i] * 4096 + f * 64 + g;
      float k0 = ksb[0], k1 = ksb[64], k2 = ksb[128], k3 = ksb[192];
      float q0 = kvb[0], q1 = kvb[64], q2 = kvb[128], q3 = kvb[192];
      const float* row = nf + (size_t)n * 256;
      float4 s04 = *(const float4*)(row + f);
      const float4* vr = (const float4*)(row + 64 + fq * 12);
      float4 va = vr[0], vb = vr[1], vc = vr[2];
      sks[i]    += s04.x * k0 + s04.y * k1 + s04.z * k2 + s04.w * k3;
      skv[i][0] += va.x * q0 + va.w * q1 + vb.z * q2 + vc.y * q3;
      skv[i][1] += va.y * q0 + vb.x * q1 + vb.w * q2 + vc.z * q3;
      skv[i][2] += va.z * q0 + vb.y * q1 + vc.x * q2 + vc.w * q3;
    }
  }
#pragma unroll
  for (int i = 0; i < 4; ++i) {
    float s = s3[i] * INV8;
    float vx = v3[i][0] * INV8, vy = v3[i][1] * INV8, vz = v3[i][2] * INV8;
    float vn2 = vx * vx + vy * vy + vz * vz;
    const float* wz = Wsc + spec[i] * 576 + g;
    float w0 = wz[0], w1 = wz[64], w2 = wz[128], w3 = wz[192], w4 = wz[256];
    float w5 = wz[320], w6 = wz[384], w7 = wz[448], w8 = wz[512];
    float s_o = w0 * s + w1 * s * s + w2 * vn2 + w3 * s * s * s + w4 * s * vn2;
    float vcm = w5 + w6 * s + w7 * s * s + w8 * vn2;
    xch[wv][i][0][g] = s_o;
    xch[wv][i][1][g] = vcm * vx;
    xch[wv][i][2][g] = vcm * vy;
    xch[wv][i][3][g] = vcm * vz;
  }
  __syncthreads();
  float s4[4] = {0, 0, 0, 0};
  float v4[4][3] = {{0,0,0},{0,0,0},{0,0,0},{0,0,0}};
  for (int fq = 0; fq < 16; ++fq) {
    int f = fq * 4;
    float p0 = Wpss[(f + 0) * 64 + g], p1 = Wpss[(f + 1) * 64 + g];
    float p2 = Wpss[(f + 2) * 64 + g], p3 = Wpss[(f + 3) * 64 + g];
    float q0 = Wpsv[(f + 0) * 64 + g], q1 = Wpsv[(f + 1) * 64 + g];
    float q2 = Wpsv[(f + 2) * 64 + g], q3 = Wpsv[(f + 3) * 64 + g];
#pragma unroll
    for (int i = 0; i < 4; ++i) {
      float4 so = *(const float4*)(&xch[wv][i][0][f]);
      float4 u0 = *(const float4*)(&xch[wv][i][1][f]);
      float4 u1 = *(const float4*)(&xch[wv][i][2][f]);
      float4 u2 = *(const float4*)(&xch[wv][i][3][f]);
      s4[i]    += so.x * p0 + so.y * p1 + so.z * p2 + so.w * p3;
      v4[i][0] += u0.x * q0 + u0.y * q1 + u0.z * q2 + u0.w * q3;
      v4[i][1] += u1.x * q0 + u1.y * q1 + u1.z * q2 + u1.w * q3;
      v4[i][2] += u2.x * q0 + u2.y * q1 + u2.z * q2 + u2.w * q3;
    }
  }
  float wo = Wout[g];
#pragma unroll
  for (int i = 0; i < 4; ++i) {
    int n = n0 + i;
    float sf = s4[i] * INV8 + sks[i] * INVZ;
    float fx = v4[i][0] * INV8 + skv[i][0] * INVZ;
    float fy = v4[i][1] * INV8 + skv[i][1] * INVZ;
    float fz = v4[i][2] * INV8 + skv[i][2] * INVZ;
    float* orow = out + NN + (size_t)n * 256;
    orow[g] = sf;
    orow[64 + g * 3 + 0] = fx;
    orow[64 + g * 3 + 1] = fy;
    orow[64 + g * 3 + 2] = fz;
    float tsum = sf * wo;
#pragma unroll
    for (int off = 32; off > 0; off >>= 1) tsum += __shfl_down(tsum, off);
    if (g == 0) out[n] = tsum * INV8;
  }
}

extern "C" void kernel_launch(void* const* d_in, const int* in_sizes, int n_in,
                              void* d_out, int out_size, void* d_ws, size_t ws_size,
                              hipStream_t stream) {
  (void)in_sizes; (void)n_in; (void)out_size; (void)ws_size;
  const float* vecs = (const float*)d_in[0];
  const float* nf   = (const float*)d_in[1];
  const float* re   = (const float*)d_in[2];
  const float* Wsks = (const float*)d_in[3];
  const float* Wskv = (const float*)d_in[4];
  const float* Wups = (const float*)d_in[5];
  const float* Wupv = (const float*)d_in[6];
  const float* W1   = (const float*)d_in[7];
  const float* W2   = (const float*)d_in[8];
  const float* W3   = (const float*)d_in[9];
  const float* W4   = (const float*)d_in[10];
  const float* Wdns = (const float*)d_in[11];
  const float* Wdnv = (const float*)d_in[12];
  const float* Wsc  = (const float*)d_in[13];
  const float* Wpss = (const float*)d_in[14];
  const float* Wpsv = (const float*)d_in[15];
  const float* Wout = (const float*)d_in[16];
  const int* species = (const int*)d_in[17];
  const int* snd     = (const int*)d_in[18];
  const int* rcv     = (const int*)d_in[19];

  float* ws = (float*)d_ws;
  float* s_up  = ws;                        // N*64
  float* v_up  = ws + 2097152;              // N*192
  float* acc   = ws + 8388608;              // N*256
  float* wT    = ws + 16777216;             // 25088
  int* row_st  = (int*)(ws + 16802304);     // 32769 (+pad)
  int* cursor  = (int*)(ws + 16835076);     // 32768
  int* elist   = (int*)(ws + 16867844);     // 262144
  unsigned short* m_buf = (unsigned short*)(ws + 17129988);  // EC*256 bf16

  float* W1T = wT;
  float* W3T = wT + 512;
  float* W4R = wT + 4608;

  hipMemsetAsync(cursor, 0, NN * sizeof(int), stream);
  hipMemsetAsync(acc, 0, (size_t)NN * 256 * sizeof(float), stream);
  k_wt<<<98, 256, 0, stream>>>(W1, W3, W4, wT);
  k_hist<<<EE / 256, 256, 0, stream>>>(rcv, cursor);
  k_scan<<<1, 1024, 0, stream>>>(cursor, row_st, cursor);
  k_fill<<<EE / 256, 256, 0, stream>>>(rcv, cursor, elist);
  k_up<<<2048, 256, 0, stream>>>(nf, Wups, Wupv, s_up, v_up);
  for (int c = 0; c < 2; ++c) {
    k_edge<<<EC / 128, 128, 0, stream>>>(vecs, re, W1T, W2, W3T, W4R,
                                         s_up, v_up, snd, elist,
                                         c * EC, m_buf);
    k_gather<<<NN / 4, 256, 0, stream>>>(m_buf, row_st, acc,
                                         c * EC, (c + 1) * EC);
  }
  k_post<<<2048, 256, 0, stream>>>(nf, acc, Wdns, Wdnv, Wsks, Wskv, Wsc,
                                   Wpss, Wpsv, Wout, species, (float*)d_out);
}